// Round 6
// baseline (1091.576 us; speedup 1.0000x reference)
//
#include <hip/hip_runtime.h>
#include <hip/hip_bf16.h>

#define B_ 64
#define T_ 512
#define D_ 1024
#define NCH 8   // t-chunks for c-reduction
#define TCH 64  // T_/NCH

// d_out element offsets (FLOAT32 elements)
#define OUT0_OFF 0u         // output [B,T,D]
#define OUT1_OFF 33554432u  // masks  [B,T,1]
#define OUT2_OFF 33587200u  // gcn    [B,T,D]
#define OUT3_OFF 67141632u  // att    [B,T]

typedef __attribute__((ext_vector_type(8))) short short8;
typedef __attribute__((ext_vector_type(2))) short short2v;
typedef __attribute__((ext_vector_type(4))) float f32x4;

__device__ __forceinline__ short bf16_of(float x) {
    __hip_bfloat16 h = __float2bfloat16(x);
    return *reinterpret_cast<short*>(&h);
}
__device__ __forceinline__ float f32_of(short s) {
    __hip_bfloat16 h;
    *reinterpret_cast<short*>(&h) = s;
    return __bfloat162float(h);
}

// async global->LDS, 16B per lane; LDS dest is wave-uniform base + lane*16 (HW)
__device__ __forceinline__ void gload16(const void* g, void* l) {
    __builtin_amdgcn_global_load_lds(
        (__attribute__((address_space(1))) void*)(g),
        (__attribute__((address_space(3))) void*)(l), 16, 0, 0);
}

// ---------------- pool: subj[b,d] = max_t (subj_pos==0) gcn[b,t,d] ----------------
__global__ __launch_bounds__(256) void pool_kernel(const float* __restrict__ gcn,
                                                   const int* __restrict__ subj_pos,
                                                   float* __restrict__ subj) {
    __shared__ int keep[T_];
    int b = blockIdx.y;
    int d = blockIdx.x * 256 + threadIdx.x;
    for (int t = threadIdx.x; t < T_; t += 256) keep[t] = (subj_pos[b * T_ + t] == 0);
    __syncthreads();
    const float* gb = gcn + (size_t)b * T_ * D_;
    float mx = -1e12f;
    for (int t = 0; t < T_; t++) {
        float v = gb[(size_t)t * D_ + d];
        if (keep[t]) mx = fmaxf(mx, v);
    }
    subj[b * D_ + d] = mx;
}

// ---------------- q = relu([subj,subj] @ Wq + bq) ----------------
__global__ __launch_bounds__(256) void mv_q(const float* __restrict__ subj,
                                            const float* __restrict__ Wq,
                                            const float* __restrict__ bq,
                                            float* __restrict__ q) {
    __shared__ float sv[D_];
    int b = blockIdx.y;
    int j = blockIdx.x * 256 + threadIdx.x;
    for (int i = threadIdx.x; i < D_; i += 256) sv[i] = subj[b * D_ + i];
    __syncthreads();
    float acc = bq[j];
    for (int i = 0; i < 2 * D_; i++) acc += sv[i & (D_ - 1)] * Wq[(size_t)i * D_ + j];
    q[b * D_ + j] = fmaxf(acc, 0.f);
}

// ---------------- tvec = relu([q, 0] @ Wc + bc) ----------------
__global__ __launch_bounds__(256) void mv_t(const float* __restrict__ q,
                                            const float* __restrict__ Wc,
                                            const float* __restrict__ bc,
                                            float* __restrict__ tv) {
    __shared__ float sv[D_];
    int b = blockIdx.y;
    int j = blockIdx.x * 256 + threadIdx.x;
    for (int i = threadIdx.x; i < D_; i += 256) sv[i] = q[b * D_ + i];
    __syncthreads();
    float acc = bc[j];
    for (int i = 0; i < D_; i++) acc += sv[i] * Wc[(size_t)i * D_ + j];
    tv[b * D_ + j] = fmaxf(acc, 0.f);
}

// ---------------- m = relu([c, subj, subj] @ Wm + bm) ----------------
__global__ __launch_bounds__(256) void mv_m(const float* __restrict__ cbuf,
                                            const float* __restrict__ subj,
                                            const float* __restrict__ Wm,
                                            const float* __restrict__ bm,
                                            float* __restrict__ m) {
    __shared__ float sc[D_];
    __shared__ float ss[D_];
    int b = blockIdx.y;
    int j = blockIdx.x * 256 + threadIdx.x;
    for (int i = threadIdx.x; i < D_; i += 256) {
        sc[i] = cbuf[b * D_ + i];
        ss[i] = subj[b * D_ + i];
    }
    __syncthreads();
    float acc = bm[j];
    for (int i = 0; i < 3 * D_; i++) {
        float v = (i < D_) ? sc[i] : ss[(i - D_) & (D_ - 1)];
        acc += v * Wm[(size_t)i * D_ + j];
    }
    m[b * D_ + j] = fmaxf(acc, 0.f);
}

// ---------------- u = WK@bQ, w = WQ@bK, alpha = bK.bQ ----------------
__global__ __launch_bounds__(256) void vecs_kernel(const float* __restrict__ WKm,
                                                   const float* __restrict__ WQm,
                                                   const float* __restrict__ bKv,
                                                   const float* __restrict__ bQv,
                                                   float* __restrict__ u,
                                                   float* __restrict__ w,
                                                   float* __restrict__ alpha) {
    int tid = threadIdx.x, wave = tid >> 6, lane = tid & 63;
    int row = blockIdx.x * 4 + wave;
    float s1 = 0.f, s2 = 0.f;
    for (int c = lane; c < D_; c += 64) {
        s1 += WKm[(size_t)row * D_ + c] * bQv[c];
        s2 += WQm[(size_t)row * D_ + c] * bKv[c];
    }
    #pragma unroll
    for (int off = 32; off; off >>= 1) {
        s1 += __shfl_xor(s1, off);
        s2 += __shfl_xor(s2, off);
    }
    if (lane == 0) { u[row] = s1; w[row] = s2; }
    if (blockIdx.x == 0 && wave == 0) {
        float a = 0.f;
        for (int c = lane; c < D_; c += 64) a += bKv[c] * bQv[c];
        #pragma unroll
        for (int off = 32; off; off >>= 1) a += __shfl_xor(a, off);
        if (lane == 0) alpha[0] = a;
    }
}

// ---- fused row dots: Gu[r]=g.u+alpha, Gw[r]=g.w, lg[r]=g.(tv[b]*Wk)+bk  (1 wave/row) ----
__global__ __launch_bounds__(256) void att_dots(const float* __restrict__ gcn,
                                                const float* __restrict__ u,
                                                const float* __restrict__ w,
                                                const float* __restrict__ tv,
                                                const float* __restrict__ Wk,
                                                const float* __restrict__ alpha,
                                                const float* __restrict__ bk,
                                                float* __restrict__ Gu,
                                                float* __restrict__ Gw,
                                                float* __restrict__ lg) {
    __shared__ float su[D_], sw[D_], s2[D_];
    int tid = threadIdx.x, wave = tid >> 6, lane = tid & 63;
    size_t row0 = (size_t)blockIdx.x * 4;
    int b = (int)(row0 >> 9);  // 4 rows per block share b (512 rows per b)
    for (int c = tid; c < D_; c += 256) {
        su[c] = u[c];
        sw[c] = w[c];
        s2[c] = tv[(size_t)b * D_ + c] * Wk[c];
    }
    __syncthreads();
    size_t row = row0 + wave;
    const float* g = gcn + row * D_;
    float d1 = 0.f, d2 = 0.f, d3 = 0.f;
    for (int c = lane; c < D_; c += 64) {
        float gv = g[c];
        d1 += gv * su[c];
        d2 += gv * sw[c];
        d3 += gv * s2[c];
    }
    #pragma unroll
    for (int off = 32; off; off >>= 1) {
        d1 += __shfl_xor(d1, off);
        d2 += __shfl_xor(d2, off);
        d3 += __shfl_xor(d3, off);
    }
    if (lane == 0) {
        Gu[row] = d1 + alpha[0];
        Gw[row] = d2;
        lg[row] = d3 + bk[0];
    }
}

// ---- k-softmax over T per batch, in place (lg -> normalized k) ----
__global__ __launch_bounds__(256) void ksoftmax_kernel(float* __restrict__ lg) {
    __shared__ float red[4];
    int b = blockIdx.x, tid = threadIdx.x;
    int wave = tid >> 6, lane = tid & 63;
    float* L = lg + (size_t)b * T_;
    float v0 = L[tid], v1 = L[tid + 256];
    float mx = fmaxf(v0, v1);
    #pragma unroll
    for (int off = 32; off; off >>= 1) mx = fmaxf(mx, __shfl_xor(mx, off));
    if (lane == 0) red[wave] = mx;
    __syncthreads();
    mx = fmaxf(fmaxf(red[0], red[1]), fmaxf(red[2], red[3]));
    __syncthreads();
    float e0 = expf(v0 - mx), e1 = expf(v1 - mx);
    float zs = e0 + e1;
    #pragma unroll
    for (int off = 32; off; off >>= 1) zs += __shfl_xor(zs, off);
    if (lane == 0) red[wave] = zs;
    __syncthreads();
    float invZ = 1.f / (red[0] + red[1] + red[2] + red[3]);
    L[tid] = e0 * invZ;
    L[tid + 256] = e1 * invZ;
}

// ---- partial c: part[(b*NCH+ch)*D+d] = sum_{t in chunk} k[b,t]*g[b,t,d] ----
__global__ __launch_bounds__(256) void csum_part(const float* __restrict__ gcn,
                                                 const float* __restrict__ k,
                                                 float* __restrict__ part) {
    __shared__ float kv[TCH];
    int d = blockIdx.x * 256 + threadIdx.x;
    int ch = blockIdx.y, b = blockIdx.z;
    if (threadIdx.x < TCH) kv[threadIdx.x] = k[(size_t)b * T_ + ch * TCH + threadIdx.x];
    __syncthreads();
    const float* gb = gcn + ((size_t)b * T_ + ch * TCH) * D_ + d;
    float acc = 0.f;
    #pragma unroll 4
    for (int i = 0; i < TCH; i++) acc += kv[i] * gb[(size_t)i * D_];
    part[((size_t)b * NCH + ch) * D_ + d] = acc;
}

// ---- reduce partials: c[b,d] = sum_ch part ----
__global__ __launch_bounds__(256) void csum_reduce(const float* __restrict__ part,
                                                   float* __restrict__ cbuf) {
    int d = blockIdx.x * 256 + threadIdx.x;
    int b = blockIdx.y;
    float acc = 0.f;
    #pragma unroll
    for (int ch = 0; ch < NCH; ch++) acc += part[((size_t)b * NCH + ch) * D_ + d];
    cbuf[(size_t)b * D_ + d] = acc;
}

// ---------------- split f32 -> hi/lo bf16 interleaved along last dim ----------------
__global__ __launch_bounds__(256) void split_kernel(const float* __restrict__ in,
                                                    short* __restrict__ out, size_t n4) {
    size_t i = (size_t)blockIdx.x * 256 + threadIdx.x;
    size_t stride = (size_t)gridDim.x * 256;
    for (; i < n4; i += stride) {
        f32x4 v = ((const f32x4*)in)[i];
        short8 o;
        #pragma unroll
        for (int j = 0; j < 4; j++) {
            short hi = bf16_of(v[j]);
            float r = v[j] - f32_of(hi);
            o[2 * j] = hi;
            o[2 * j + 1] = bf16_of(r);
        }
        ((short8*)out)[i] = o;
    }
}

// ---------------- out[z][c][r] = bf16(in[z][r][c]) ; R,C multiples of 32 ----------------
__global__ __launch_bounds__(256) void transpose_kernel(const float* __restrict__ in, size_t sIn,
                                                        short* __restrict__ out, size_t sOut,
                                                        int R, int C) {
    __shared__ float tile[32][33];
    int z = blockIdx.z;
    in += (size_t)z * sIn;
    out += (size_t)z * sOut;
    int c0 = blockIdx.x * 32, r0 = blockIdx.y * 32;
    int tx = threadIdx.x & 31, ty = threadIdx.x >> 5;
    #pragma unroll
    for (int i = 0; i < 4; i++) {
        int r = ty + i * 8;
        tile[r][tx] = in[(size_t)(r0 + r) * C + c0 + tx];
    }
    __syncthreads();
    #pragma unroll
    for (int i = 0; i < 4; i++) {
        int c = ty + i * 8;
        out[(size_t)(c0 + c) * R + r0 + tx] = bf16_of(tile[tx][c]);
    }
}

// ================= MFMA NT bf16 GEMM: C[m,n] = sum_k A[m,k]*Bt[n,k] =================
// 128x128 tile, BK=64, 4 waves (2x2 of 64x64), 16x16x32 bf16 MFMA, f32 accum.
// Staging: global_load_lds w16, LINEAR LDS [128][64] shorts; XOR swizzle (slot16^row&7)
// applied to the GLOBAL source on stage and to the ds_read address (rule: both sides).
// MODE 0: f32 store | 1: f32 + Gu[row]+Gw[col] | 2: bf16 store
// MODE 3: f32 (acc+bV[col])*gate[z*D+col]      | 4: hi/lo split bf16 store (ldout=2N)
template <int MODE>
__global__ __launch_bounds__(256) void gemm_nt(
        const short* __restrict__ A, size_t sAz,
        const short* __restrict__ Bt, size_t sBz,
        int K, int ldout,
        float* __restrict__ Cf, short* __restrict__ Cb, size_t sCz,
        const float* __restrict__ e1, const float* __restrict__ e2) {
    __shared__ __align__(16) short As[128 * 64];
    __shared__ __align__(16) short Bs[128 * 64];
    int z = blockIdx.z;
    A += (size_t)z * sAz;
    Bt += (size_t)z * sBz;
    int t = threadIdx.x;
    int lane = t & 63, wave = t >> 6;
    int wr = wave >> 1, wc = wave & 1;
    size_t rowBase = (size_t)blockIdx.x * 128;
    size_t colBase = (size_t)blockIdx.y * 128;

    // ---- staging addresses: wave handles chunks wave*4+i (i=0..3); chunk = 8 rows x 128B
    int rlo = lane >> 3;                 // row within chunk 0..7
    int src16 = (lane & 7) ^ rlo;        // inverse-swizzled 16B slot in global row
    const short* gA[4];
    const short* gB[4];
    short* lA[4];
    short* lB[4];
    #pragma unroll
    for (int i = 0; i < 4; i++) {
        int ch = wave * 4 + i;
        int row = ch * 8 + rlo;
        gA[i] = A + (rowBase + row) * (size_t)K + src16 * 8;
        gB[i] = Bt + (colBase + row) * (size_t)K + src16 * 8;
        lA[i] = As + ch * 512;  // 1024B chunk; HW adds lane*16
        lB[i] = Bs + ch * 512;
    }

    f32x4 acc[4][4] = {};
    for (int kb = 0; kb < K; kb += 64) {
        __syncthreads();  // previous compute done reading LDS
        #pragma unroll
        for (int i = 0; i < 4; i++) {
            gload16(gA[i] + kb, lA[i]);
            gload16(gB[i] + kb, lB[i]);
        }
        __syncthreads();  // compiler drains vmcnt(0) before barrier
        #pragma unroll
        for (int kk = 0; kk < 2; kk++) {
            int ko16 = kk * 4 + (lane >> 4);
            int sw = ko16 ^ (lane & 7);  // row&7 == lane&7 for our row pattern
            short8 af[4], bfr[4];
            #pragma unroll
            for (int i = 0; i < 4; i++) {
                int row = wr * 64 + i * 16 + (lane & 15);
                af[i] = *(const short8*)(As + row * 64 + (sw << 3));
            }
            #pragma unroll
            for (int j = 0; j < 4; j++) {
                int row = wc * 64 + j * 16 + (lane & 15);
                bfr[j] = *(const short8*)(Bs + row * 64 + (sw << 3));
            }
            #pragma unroll
            for (int i = 0; i < 4; i++)
                #pragma unroll
                for (int j = 0; j < 4; j++)
                    acc[i][j] = __builtin_amdgcn_mfma_f32_16x16x32_bf16(af[i], bfr[j], acc[i][j], 0, 0, 0);
        }
    }
    #pragma unroll
    for (int i = 0; i < 4; i++) {
        #pragma unroll
        for (int j = 0; j < 4; j++) {
            #pragma unroll
            for (int r = 0; r < 4; r++) {
                size_t row = rowBase + wr * 64 + i * 16 + (lane >> 4) * 4 + r;
                size_t col = colBase + wc * 64 + j * 16 + (lane & 15);
                float v = acc[i][j][r];
                if (MODE == 0) {
                    Cf[z * sCz + row * ldout + col] = v;
                } else if (MODE == 1) {
                    Cf[z * sCz + row * ldout + col] = v + e1[z * T_ + row] + e2[z * T_ + col];
                } else if (MODE == 2) {
                    Cb[z * sCz + row * ldout + col] = bf16_of(v);
                } else if (MODE == 3) {
                    Cf[z * sCz + row * ldout + col] = (v + e1[col]) * e2[(size_t)z * D_ + col];
                } else {
                    short hi = bf16_of(v);
                    float rr = v - f32_of(hi);
                    short2v o;
                    o[0] = hi;
                    o[1] = bf16_of(rr);
                    *(short2v*)(&Cb[row * (size_t)ldout + 2 * col]) = o;
                }
            }
        }
    }
}

// ---------------- per-row: att out (f32) + probs out (bf16) ----------------
__global__ __launch_bounds__(64) void softmax_att(const float* __restrict__ S,
                                                  short* __restrict__ probs,
                                                  float* __restrict__ att) {
    const float SCALE = 0.03125f;  // 1/sqrt(1024)
    int t = blockIdx.x, z = blockIdx.y, lane = threadIdx.x;
    const float* row = S + ((size_t)z * T_ + t) * T_;
    short* prow = probs + ((size_t)z * T_ + t) * T_;
    float v[8];
    float mx = -1e30f;
    #pragma unroll
    for (int k = 0; k < 8; k++) {
        v[k] = row[lane + k * 64];
        mx = fmaxf(mx, v[k]);
    }
    #pragma unroll
    for (int off = 32; off; off >>= 1) mx = fmaxf(mx, __shfl_xor(mx, off));
    float z1 = 0.f, z2 = 0.f, dg = 0.f;
    #pragma unroll
    for (int k = 0; k < 8; k++) {
        float x = v[k] - mx;
        float e1 = expf(x);
        float e2 = expf(x * SCALE);
        z1 += e1;
        z2 += e2;
        if (lane + k * 64 == t) dg = e1;
        v[k] = e2;
    }
    #pragma unroll
    for (int off = 32; off; off >>= 1) {
        z1 += __shfl_xor(z1, off);
        z2 += __shfl_xor(z2, off);
        dg += __shfl_xor(dg, off);
    }
    float inv2 = 1.f / z2;
    #pragma unroll
    for (int k = 0; k < 8; k++) prow[lane + k * 64] = bf16_of(v[k] * inv2);
    if (lane == 0) att[z * T_ + t] = SCALE * (1.f - dg / z1);
}

// ---------------- masks passthrough (f32) ----------------
__global__ __launch_bounds__(256) void masks_kernel(const int* __restrict__ masks,
                                                    float* __restrict__ out_masks) {
    int i = blockIdx.x * 256 + threadIdx.x;
    if (i < B_ * T_) out_masks[i] = (float)masks[i];
}

extern "C" void kernel_launch(void* const* d_in, const int* in_sizes, int n_in,
                              void* d_out, int out_size, void* d_ws, size_t ws_size,
                              hipStream_t stream) {
    const float* gcn = (const float*)d_in[0];
    const int* subj_pos = (const int*)d_in[1];
    const int* masks = (const int*)d_in[3];
    const float* Wq = (const float*)d_in[4];
    const float* bq = (const float*)d_in[5];
    const float* Wc = (const float*)d_in[6];
    const float* bc = (const float*)d_in[7];
    const float* Wk = (const float*)d_in[8];
    const float* bk = (const float*)d_in[9];
    const float* Wm = (const float*)d_in[10];
    const float* bm = (const float*)d_in[11];
    const float* WK = (const float*)d_in[12];
    const float* bK = (const float*)d_in[13];
    const float* WQ = (const float*)d_in[14];
    const float* bQ = (const float*)d_in[15];
    const float* WV = (const float*)d_in[16];
    const float* bV = (const float*)d_in[17];

    float* out = (float*)d_out;

    // ---- workspace layout (bytes, 256-aligned chunks) ----
    char* p = (char*)d_ws;
    auto alloc = [&](size_t bytes) {
        char* r = p;
        p += (bytes + 255) & ~(size_t)255;
        return r;
    };
    float* subj = (float*)alloc(B_ * D_ * 4);
    float* qv   = (float*)alloc(B_ * D_ * 4);
    float* tv   = (float*)alloc(B_ * D_ * 4);
    float* cb   = (float*)alloc(B_ * D_ * 4);
    float* mb   = (float*)alloc(B_ * D_ * 4);
    float* u    = (float*)alloc(D_ * 4);
    float* w    = (float*)alloc(D_ * 4);
    float* alph = (float*)alloc(256);
    float* Gu   = (float*)alloc(B_ * T_ * 4);
    float* Gw   = (float*)alloc(B_ * T_ * 4);
    float* lg   = (float*)alloc(B_ * T_ * 4);
    float* part = (float*)alloc((size_t)B_ * NCH * D_ * 4);
    float* Pt   = (float*)alloc((size_t)D_ * D_ * 4);
    short* WKs  = (short*)alloc((size_t)D_ * 2 * D_ * 2);
    short* WQs  = (short*)alloc((size_t)D_ * 2 * D_ * 2);
    short* Pts  = (short*)alloc((size_t)D_ * 2 * D_ * 2);
    short* WVt  = (short*)alloc((size_t)D_ * D_ * 2);

    size_t fixedBytes = (size_t)(p - (char*)d_ws);
    // per-chunk bytes (nc batches): Gs + Ys + Gt + S + probs + Zs
    const size_t perBatch = (size_t)T_ * 2 * D_ * 2   // Gs
                          + (size_t)T_ * 2 * D_ * 2   // Ys
                          + (size_t)D_ * T_ * 2       // Gt
                          + (size_t)T_ * T_ * 4       // S
                          + (size_t)T_ * T_ * 2       // probs
                          + (size_t)T_ * D_ * 2;      // Zs
    int nc = 64;
    while (nc > 1 && fixedBytes + (size_t)nc * perBatch + 4096 > ws_size) nc >>= 1;

    short* Gs_c    = (short*)alloc((size_t)nc * T_ * 2 * D_ * 2);
    short* Ys_c    = (short*)alloc((size_t)nc * T_ * 2 * D_ * 2);
    short* Gt_c    = (short*)alloc((size_t)nc * D_ * T_ * 2);
    float* S_c     = (float*)alloc((size_t)nc * T_ * T_ * 4);
    short* probs_c = (short*)alloc((size_t)nc * T_ * T_ * 2);
    short* Zs_c    = (short*)alloc((size_t)nc * T_ * D_ * 2);

    // ---- small path: gate m and pooled vectors (parallel c-attention) ----
    pool_kernel<<<dim3(D_ / 256, B_), 256, 0, stream>>>(gcn, subj_pos, subj);
    mv_q<<<dim3(D_ / 256, B_), 256, 0, stream>>>(subj, Wq, bq, qv);
    mv_t<<<dim3(D_ / 256, B_), 256, 0, stream>>>(qv, Wc, bc, tv);
    vecs_kernel<<<D_ / 4, 256, 0, stream>>>(WK, WQ, bK, bQ, u, w, alph);
    att_dots<<<B_ * T_ / 4, 256, 0, stream>>>(gcn, u, w, tv, Wk, alph, bk, Gu, Gw, lg);
    ksoftmax_kernel<<<B_, 256, 0, stream>>>(lg);
    csum_part<<<dim3(D_ / 256, NCH, B_), 256, 0, stream>>>(gcn, lg, part);
    csum_reduce<<<dim3(D_ / 256, B_), 256, 0, stream>>>(part, cb);
    mv_m<<<dim3(D_ / 256, B_), 256, 0, stream>>>(cb, subj, Wm, bm, mb);

    // ---- factorization precompute (split precision) ----
    split_kernel<<<1024, 256, 0, stream>>>(WK, WKs, (size_t)D_ * D_ / 4);
    split_kernel<<<1024, 256, 0, stream>>>(WQ, WQs, (size_t)D_ * D_ / 4);
    // Pt[c,a] = sum_k WQ[c,k]*WK[a,k]  (= P[a,c])
    gemm_nt<0><<<dim3(8, 8, 1), 256, 0, stream>>>(WQs, 0, WKs, 0, 2 * D_, D_,
                                                  Pt, nullptr, 0, nullptr, nullptr);
    split_kernel<<<1024, 256, 0, stream>>>(Pt, Pts, (size_t)D_ * D_ / 4);
    // WVt[d,k] = WV[k,d]
    transpose_kernel<<<dim3(32, 32, 1), 256, 0, stream>>>(WV, 0, WVt, 0, D_, D_);

    // ---- chunked attention ----
    for (int b0 = 0; b0 < B_; b0 += nc) {
        const float* Gc = gcn + (size_t)b0 * T_ * D_;
        // Gs = split(G), Gt = bf16(G^T)
        split_kernel<<<2048, 256, 0, stream>>>(Gc, Gs_c, (size_t)nc * T_ * D_ / 4);
        transpose_kernel<<<dim3(D_ / 32, T_ / 32, nc), 256, 0, stream>>>(
            Gc, (size_t)T_ * D_, Gt_c, (size_t)D_ * T_, T_, D_);
        // Y = G@P (split in, split-store out): A=Gs [nc*T, 2D], Bt=Pts [D, 2D]
        gemm_nt<4><<<dim3(nc * T_ / 128, D_ / 128, 1), 256, 0, stream>>>(
            Gs_c, 0, Pts, 0, 2 * D_, 2 * D_, nullptr, Ys_c, 0, nullptr, nullptr);
        // S = Y@G^T + Gu + Gw : A=Ys(z), Bt=Gs(z), K=2D
        gemm_nt<1><<<dim3(T_ / 128, T_ / 128, nc), 256, 0, stream>>>(
            Ys_c, (size_t)T_ * 2 * D_, Gs_c, (size_t)T_ * 2 * D_, 2 * D_, T_,
            S_c, nullptr, (size_t)T_ * T_, Gu + (size_t)b0 * T_, Gw + (size_t)b0 * T_);
        // softmax: att (f32) + probs (bf16)
        softmax_att<<<dim3(T_, nc), 64, 0, stream>>>(S_c, probs_c, out + OUT3_OFF + (size_t)b0 * T_);
        // Z = probs@G : A=probs(z) [T,T], Bt=Gt(z) [D,T], K=T -> bf16
        gemm_nt<2><<<dim3(T_ / 128, D_ / 128, nc), 256, 0, stream>>>(
            probs_c, (size_t)T_ * T_, Gt_c, (size_t)D_ * T_, T_, D_,
            nullptr, Zs_c, (size_t)T_ * D_, nullptr, nullptr);
        // out0 = (Z@WV + bV) * m : A=Zs(z) [T,D], Bt=WVt [D,D], K=D
        gemm_nt<3><<<dim3(T_ / 128, D_ / 128, nc), 256, 0, stream>>>(
            Zs_c, (size_t)T_ * D_, WVt, 0, D_, D_,
            out + OUT0_OFF + (size_t)b0 * T_ * D_, nullptr, (size_t)T_ * D_,
            bV, mb + (size_t)b0 * D_);
    }

    // ---- passthroughs ----
    hipMemcpyAsync(out + OUT2_OFF, gcn, (size_t)B_ * T_ * D_ * sizeof(float),
                   hipMemcpyDeviceToDevice, stream);
    masks_kernel<<<(B_ * T_ + 255) / 256, 256, 0, stream>>>(masks, out + OUT1_OFF);
}

// Round 7
// 904.158 us; speedup vs baseline: 1.2073x; 1.2073x over previous
//
#include <hip/hip_runtime.h>
#include <hip/hip_bf16.h>

#define B_ 64
#define T_ 512
#define D_ 1024
#define NCH 8   // t-chunks for c-reduction
#define TCH 64  // T_/NCH

// d_out element offsets (FLOAT32 elements)
#define OUT0_OFF 0u         // output [B,T,D]
#define OUT1_OFF 33554432u  // masks  [B,T,1]
#define OUT2_OFF 33587200u  // gcn    [B,T,D]
#define OUT3_OFF 67141632u  // att    [B,T]

typedef __attribute__((ext_vector_type(8))) short short8;
typedef __attribute__((ext_vector_type(4))) float f32x4;

__device__ __forceinline__ short bf16_of(float x) {
    __hip_bfloat16 h = __float2bfloat16(x);
    return *reinterpret_cast<short*>(&h);
}

// async global->LDS, 16B per lane; LDS dest is wave-uniform base + lane*16 (HW)
__device__ __forceinline__ void gload16(const void* g, void* l) {
    __builtin_amdgcn_global_load_lds(
        (__attribute__((address_space(1))) void*)(g),
        (__attribute__((address_space(3))) void*)(l), 16, 0, 0);
}

// ---------------- pool: subj[b,d] = max_t (subj_pos==0) gcn[b,t,d] ----------------
__global__ __launch_bounds__(256) void pool_kernel(const float* __restrict__ gcn,
                                                   const int* __restrict__ subj_pos,
                                                   float* __restrict__ subj) {
    __shared__ int keep[T_];
    int b = blockIdx.y;
    int d = blockIdx.x * 256 + threadIdx.x;
    for (int t = threadIdx.x; t < T_; t += 256) keep[t] = (subj_pos[b * T_ + t] == 0);
    __syncthreads();
    const float* gb = gcn + (size_t)b * T_ * D_;
    float mx = -1e12f;
    for (int t = 0; t < T_; t++) {
        float v = gb[(size_t)t * D_ + d];
        if (keep[t]) mx = fmaxf(mx, v);
    }
    subj[b * D_ + d] = mx;
}

// ---------------- q = relu([subj,subj] @ Wq + bq) ----------------
__global__ __launch_bounds__(256) void mv_q(const float* __restrict__ subj,
                                            const float* __restrict__ Wq,
                                            const float* __restrict__ bq,
                                            float* __restrict__ q) {
    __shared__ float sv[D_];
    int b = blockIdx.y;
    int j = blockIdx.x * 256 + threadIdx.x;
    for (int i = threadIdx.x; i < D_; i += 256) sv[i] = subj[b * D_ + i];
    __syncthreads();
    float acc = bq[j];
    for (int i = 0; i < 2 * D_; i++) acc += sv[i & (D_ - 1)] * Wq[(size_t)i * D_ + j];
    q[b * D_ + j] = fmaxf(acc, 0.f);
}

// ---------------- tvec = relu([q, 0] @ Wc + bc) ----------------
__global__ __launch_bounds__(256) void mv_t(const float* __restrict__ q,
                                            const float* __restrict__ Wc,
                                            const float* __restrict__ bc,
                                            float* __restrict__ tv) {
    __shared__ float sv[D_];
    int b = blockIdx.y;
    int j = blockIdx.x * 256 + threadIdx.x;
    for (int i = threadIdx.x; i < D_; i += 256) sv[i] = q[b * D_ + i];
    __syncthreads();
    float acc = bc[j];
    for (int i = 0; i < D_; i++) acc += sv[i] * Wc[(size_t)i * D_ + j];
    tv[b * D_ + j] = fmaxf(acc, 0.f);
}

// ---------------- m = relu([c, subj, subj] @ Wm + bm) ----------------
__global__ __launch_bounds__(256) void mv_m(const float* __restrict__ cbuf,
                                            const float* __restrict__ subj,
                                            const float* __restrict__ Wm,
                                            const float* __restrict__ bm,
                                            float* __restrict__ m) {
    __shared__ float sc[D_];
    __shared__ float ss[D_];
    int b = blockIdx.y;
    int j = blockIdx.x * 256 + threadIdx.x;
    for (int i = threadIdx.x; i < D_; i += 256) {
        sc[i] = cbuf[b * D_ + i];
        ss[i] = subj[b * D_ + i];
    }
    __syncthreads();
    float acc = bm[j];
    for (int i = 0; i < 3 * D_; i++) {
        float v = (i < D_) ? sc[i] : ss[(i - D_) & (D_ - 1)];
        acc += v * Wm[(size_t)i * D_ + j];
    }
    m[b * D_ + j] = fmaxf(acc, 0.f);
}

// ---------------- u = WK@bQ, w = WQ@bK, alpha = bK.bQ ----------------
__global__ __launch_bounds__(256) void vecs_kernel(const float* __restrict__ WKm,
                                                   const float* __restrict__ WQm,
                                                   const float* __restrict__ bKv,
                                                   const float* __restrict__ bQv,
                                                   float* __restrict__ u,
                                                   float* __restrict__ w,
                                                   float* __restrict__ alpha) {
    int tid = threadIdx.x, wave = tid >> 6, lane = tid & 63;
    int row = blockIdx.x * 4 + wave;
    float s1 = 0.f, s2 = 0.f;
    for (int c = lane; c < D_; c += 64) {
        s1 += WKm[(size_t)row * D_ + c] * bQv[c];
        s2 += WQm[(size_t)row * D_ + c] * bKv[c];
    }
    #pragma unroll
    for (int off = 32; off; off >>= 1) {
        s1 += __shfl_xor(s1, off);
        s2 += __shfl_xor(s2, off);
    }
    if (lane == 0) { u[row] = s1; w[row] = s2; }
    if (blockIdx.x == 0 && wave == 0) {
        float a = 0.f;
        for (int c = lane; c < D_; c += 64) a += bKv[c] * bQv[c];
        #pragma unroll
        for (int off = 32; off; off >>= 1) a += __shfl_xor(a, off);
        if (lane == 0) alpha[0] = a;
    }
}

// ---- fused row dots: Gu[r]=g.u+alpha, Gw[r]=g.w, lg[r]=g.(tv[b]*Wk)+bk  (1 wave/row) ----
__global__ __launch_bounds__(256) void att_dots(const float* __restrict__ gcn,
                                                const float* __restrict__ u,
                                                const float* __restrict__ w,
                                                const float* __restrict__ tv,
                                                const float* __restrict__ Wk,
                                                const float* __restrict__ alpha,
                                                const float* __restrict__ bk,
                                                float* __restrict__ Gu,
                                                float* __restrict__ Gw,
                                                float* __restrict__ lg) {
    __shared__ float su[D_], sw[D_], s2[D_];
    int tid = threadIdx.x, wave = tid >> 6, lane = tid & 63;
    size_t row0 = (size_t)blockIdx.x * 4;
    int b = (int)(row0 >> 9);  // 4 rows per block share b (512 rows per b)
    for (int c = tid; c < D_; c += 256) {
        su[c] = u[c];
        sw[c] = w[c];
        s2[c] = tv[(size_t)b * D_ + c] * Wk[c];
    }
    __syncthreads();
    size_t row = row0 + wave;
    const float* g = gcn + row * D_;
    float d1 = 0.f, d2 = 0.f, d3 = 0.f;
    for (int c = lane; c < D_; c += 64) {
        float gv = g[c];
        d1 += gv * su[c];
        d2 += gv * sw[c];
        d3 += gv * s2[c];
    }
    #pragma unroll
    for (int off = 32; off; off >>= 1) {
        d1 += __shfl_xor(d1, off);
        d2 += __shfl_xor(d2, off);
        d3 += __shfl_xor(d3, off);
    }
    if (lane == 0) {
        Gu[row] = d1 + alpha[0];
        Gw[row] = d2;
        lg[row] = d3 + bk[0];
    }
}

// ---- k-softmax over T per batch, in place (lg -> normalized k) ----
__global__ __launch_bounds__(256) void ksoftmax_kernel(float* __restrict__ lg) {
    __shared__ float red[4];
    int b = blockIdx.x, tid = threadIdx.x;
    int wave = tid >> 6, lane = tid & 63;
    float* L = lg + (size_t)b * T_;
    float v0 = L[tid], v1 = L[tid + 256];
    float mx = fmaxf(v0, v1);
    #pragma unroll
    for (int off = 32; off; off >>= 1) mx = fmaxf(mx, __shfl_xor(mx, off));
    if (lane == 0) red[wave] = mx;
    __syncthreads();
    mx = fmaxf(fmaxf(red[0], red[1]), fmaxf(red[2], red[3]));
    __syncthreads();
    float e0 = expf(v0 - mx), e1 = expf(v1 - mx);
    float zs = e0 + e1;
    #pragma unroll
    for (int off = 32; off; off >>= 1) zs += __shfl_xor(zs, off);
    if (lane == 0) red[wave] = zs;
    __syncthreads();
    float invZ = 1.f / (red[0] + red[1] + red[2] + red[3]);
    L[tid] = e0 * invZ;
    L[tid + 256] = e1 * invZ;
}

// ---- partial c: part[(b*NCH+ch)*D+d] = sum_{t in chunk} k[b,t]*g[b,t,d] ----
__global__ __launch_bounds__(256) void csum_part(const float* __restrict__ gcn,
                                                 const float* __restrict__ k,
                                                 float* __restrict__ part) {
    __shared__ float kv[TCH];
    int d = blockIdx.x * 256 + threadIdx.x;
    int ch = blockIdx.y, b = blockIdx.z;
    if (threadIdx.x < TCH) kv[threadIdx.x] = k[(size_t)b * T_ + ch * TCH + threadIdx.x];
    __syncthreads();
    const float* gb = gcn + ((size_t)b * T_ + ch * TCH) * D_ + d;
    float acc = 0.f;
    #pragma unroll 4
    for (int i = 0; i < TCH; i++) acc += kv[i] * gb[(size_t)i * D_];
    part[((size_t)b * NCH + ch) * D_ + d] = acc;
}

// ---- reduce partials: c[b,d] = sum_ch part ----
__global__ __launch_bounds__(256) void csum_reduce(const float* __restrict__ part,
                                                   float* __restrict__ cbuf) {
    int d = blockIdx.x * 256 + threadIdx.x;
    int b = blockIdx.y;
    float acc = 0.f;
    #pragma unroll
    for (int ch = 0; ch < NCH; ch++) acc += part[((size_t)b * NCH + ch) * D_ + d];
    cbuf[(size_t)b * D_ + d] = acc;
}

// ---------------- plain cast f32 -> bf16, vectorized ----------------
__global__ __launch_bounds__(256) void cast_kernel(const float* __restrict__ in,
                                                   short* __restrict__ out, size_t n8) {
    size_t i = (size_t)blockIdx.x * 256 + threadIdx.x;
    size_t stride = (size_t)gridDim.x * 256;
    for (; i < n8; i += stride) {
        f32x4 v0 = ((const f32x4*)in)[2 * i];
        f32x4 v1 = ((const f32x4*)in)[2 * i + 1];
        short8 o;
        #pragma unroll
        for (int j = 0; j < 4; j++) {
            o[j] = bf16_of(v0[j]);
            o[4 + j] = bf16_of(v1[j]);
        }
        ((short8*)out)[i] = o;
    }
}

// ---- fused G-prep per chunk: Gs=bf16(G), Gt=bf16(G^T), o2=G (f32 passthrough) ----
__global__ __launch_bounds__(256) void prep_kernel(const float* __restrict__ in,
                                                   short* __restrict__ gs,
                                                   short* __restrict__ gt,
                                                   float* __restrict__ o2) {
    __shared__ float tile[32][33];
    int z = blockIdx.z;
    in += (size_t)z * T_ * D_;
    gs += (size_t)z * T_ * D_;
    gt += (size_t)z * D_ * T_;
    o2 += (size_t)z * T_ * D_;
    int c0 = blockIdx.x * 32, r0 = blockIdx.y * 32;
    int tx = threadIdx.x & 31, ty = threadIdx.x >> 5;
    #pragma unroll
    for (int i = 0; i < 4; i++) {
        int r = ty + i * 8;
        size_t idx = (size_t)(r0 + r) * D_ + c0 + tx;
        float v = in[idx];
        tile[r][tx] = v;
        o2[idx] = v;
        gs[idx] = bf16_of(v);
    }
    __syncthreads();
    #pragma unroll
    for (int i = 0; i < 4; i++) {
        int c = ty + i * 8;
        gt[(size_t)(c0 + c) * T_ + r0 + tx] = bf16_of(tile[tx][c]);
    }
}

// ---------------- out[z][c][r] = bf16(in[z][r][c]) ; R,C multiples of 32 ----------------
__global__ __launch_bounds__(256) void transpose_kernel(const float* __restrict__ in, size_t sIn,
                                                        short* __restrict__ out, size_t sOut,
                                                        int R, int C) {
    __shared__ float tile[32][33];
    int z = blockIdx.z;
    in += (size_t)z * sIn;
    out += (size_t)z * sOut;
    int c0 = blockIdx.x * 32, r0 = blockIdx.y * 32;
    int tx = threadIdx.x & 31, ty = threadIdx.x >> 5;
    #pragma unroll
    for (int i = 0; i < 4; i++) {
        int r = ty + i * 8;
        tile[r][tx] = in[(size_t)(r0 + r) * C + c0 + tx];
    }
    __syncthreads();
    #pragma unroll
    for (int i = 0; i < 4; i++) {
        int c = ty + i * 8;
        out[(size_t)(c0 + c) * R + r0 + tx] = bf16_of(tile[tx][c]);
    }
}

// ================= MFMA NT bf16 GEMM: C[m,n] = sum_k A[m,k]*Bt[n,k] =================
// 128x128 tile, BK=64, 4 waves (2x2 of 64x64), 16x16x32 bf16 MFMA, f32 accum.
// Staging: global_load_lds w16, LINEAR LDS [128][64] shorts; XOR swizzle (slot16^row&7)
// applied to the GLOBAL source on stage and to the ds_read address (both sides).
// MODE 0: f32 store | 1: f32 + Gu[row]+Gw[col] | 2: bf16 store
// MODE 3: f32 (acc+bV[col])*gate[z*D+col]
template <int MODE>
__global__ __launch_bounds__(256) void gemm_nt(
        const short* __restrict__ A, size_t sAz,
        const short* __restrict__ Bt, size_t sBz,
        int K, int ldout,
        float* __restrict__ Cf, short* __restrict__ Cb, size_t sCz,
        const float* __restrict__ e1, const float* __restrict__ e2) {
    __shared__ __align__(16) short As[128 * 64];
    __shared__ __align__(16) short Bs[128 * 64];
    int z = blockIdx.z;
    A += (size_t)z * sAz;
    Bt += (size_t)z * sBz;
    int t = threadIdx.x;
    int lane = t & 63, wave = t >> 6;
    int wr = wave >> 1, wc = wave & 1;
    size_t rowBase = (size_t)blockIdx.x * 128;
    size_t colBase = (size_t)blockIdx.y * 128;

    // ---- staging addresses: wave handles chunks wave*4+i (i=0..3); chunk = 8 rows x 128B
    int rlo = lane >> 3;                 // row within chunk 0..7
    int src16 = (lane & 7) ^ rlo;        // inverse-swizzled 16B slot in global row
    const short* gA[4];
    const short* gB[4];
    short* lA[4];
    short* lB[4];
    #pragma unroll
    for (int i = 0; i < 4; i++) {
        int ch = wave * 4 + i;
        int row = ch * 8 + rlo;
        gA[i] = A + (rowBase + row) * (size_t)K + src16 * 8;
        gB[i] = Bt + (colBase + row) * (size_t)K + src16 * 8;
        lA[i] = As + ch * 512;  // 1024B chunk; HW adds lane*16
        lB[i] = Bs + ch * 512;
    }

    f32x4 acc[4][4] = {};
    for (int kb = 0; kb < K; kb += 64) {
        __syncthreads();  // previous compute done reading LDS
        #pragma unroll
        for (int i = 0; i < 4; i++) {
            gload16(gA[i] + kb, lA[i]);
            gload16(gB[i] + kb, lB[i]);
        }
        __syncthreads();  // compiler drains vmcnt(0) before barrier
        #pragma unroll
        for (int kk = 0; kk < 2; kk++) {
            int ko16 = kk * 4 + (lane >> 4);
            int sw = ko16 ^ (lane & 7);  // row&7 == lane&7 for our row pattern
            short8 af[4], bfr[4];
            #pragma unroll
            for (int i = 0; i < 4; i++) {
                int row = wr * 64 + i * 16 + (lane & 15);
                af[i] = *(const short8*)(As + row * 64 + (sw << 3));
            }
            #pragma unroll
            for (int j = 0; j < 4; j++) {
                int row = wc * 64 + j * 16 + (lane & 15);
                bfr[j] = *(const short8*)(Bs + row * 64 + (sw << 3));
            }
            #pragma unroll
            for (int i = 0; i < 4; i++)
                #pragma unroll
                for (int j = 0; j < 4; j++)
                    acc[i][j] = __builtin_amdgcn_mfma_f32_16x16x32_bf16(af[i], bfr[j], acc[i][j], 0, 0, 0);
        }
    }
    #pragma unroll
    for (int i = 0; i < 4; i++) {
        #pragma unroll
        for (int j = 0; j < 4; j++) {
            #pragma unroll
            for (int r = 0; r < 4; r++) {
                size_t row = rowBase + wr * 64 + i * 16 + (lane >> 4) * 4 + r;
                size_t col = colBase + wc * 64 + j * 16 + (lane & 15);
                float v = acc[i][j][r];
                if (MODE == 0) {
                    Cf[z * sCz + row * ldout + col] = v;
                } else if (MODE == 1) {
                    Cf[z * sCz + row * ldout + col] = v + e1[z * T_ + row] + e2[z * T_ + col];
                } else if (MODE == 2) {
                    Cb[z * sCz + row * ldout + col] = bf16_of(v);
                } else {
                    Cf[z * sCz + row * ldout + col] = (v + e1[col]) * e2[(size_t)z * D_ + col];
                }
            }
        }
    }
}

// ---------------- per-row: att out (f32) + probs out (bf16) ----------------
__global__ __launch_bounds__(64) void softmax_att(const float* __restrict__ S,
                                                  short* __restrict__ probs,
                                                  float* __restrict__ att) {
    const float SCALE = 0.03125f;  // 1/sqrt(1024)
    int t = blockIdx.x, z = blockIdx.y, lane = threadIdx.x;
    const float* row = S + ((size_t)z * T_ + t) * T_;
    short* prow = probs + ((size_t)z * T_ + t) * T_;
    float v[8];
    float mx = -1e30f;
    #pragma unroll
    for (int k = 0; k < 8; k++) {
        v[k] = row[lane + k * 64];
        mx = fmaxf(mx, v[k]);
    }
    #pragma unroll
    for (int off = 32; off; off >>= 1) mx = fmaxf(mx, __shfl_xor(mx, off));
    float z1 = 0.f, z2 = 0.f, dg = 0.f;
    #pragma unroll
    for (int k = 0; k < 8; k++) {
        float x = v[k] - mx;
        float e1 = expf(x);
        float e2 = expf(x * SCALE);
        z1 += e1;
        z2 += e2;
        if (lane + k * 64 == t) dg = e1;
        v[k] = e2;
    }
    #pragma unroll
    for (int off = 32; off; off >>= 1) {
        z1 += __shfl_xor(z1, off);
        z2 += __shfl_xor(z2, off);
        dg += __shfl_xor(dg, off);
    }
    float inv2 = 1.f / z2;
    #pragma unroll
    for (int k = 0; k < 8; k++) prow[lane + k * 64] = bf16_of(v[k] * inv2);
    if (lane == 0) att[z * T_ + t] = SCALE * (1.f - dg / z1);
}

// ---------------- masks passthrough (f32) ----------------
__global__ __launch_bounds__(256) void masks_kernel(const int* __restrict__ masks,
                                                    float* __restrict__ out_masks) {
    int i = blockIdx.x * 256 + threadIdx.x;
    if (i < B_ * T_) out_masks[i] = (float)masks[i];
}

extern "C" void kernel_launch(void* const* d_in, const int* in_sizes, int n_in,
                              void* d_out, int out_size, void* d_ws, size_t ws_size,
                              hipStream_t stream) {
    const float* gcn = (const float*)d_in[0];
    const int* subj_pos = (const int*)d_in[1];
    const int* masks = (const int*)d_in[3];
    const float* Wq = (const float*)d_in[4];
    const float* bq = (const float*)d_in[5];
    const float* Wc = (const float*)d_in[6];
    const float* bc = (const float*)d_in[7];
    const float* Wk = (const float*)d_in[8];
    const float* bk = (const float*)d_in[9];
    const float* Wm = (const float*)d_in[10];
    const float* bm = (const float*)d_in[11];
    const float* WK = (const float*)d_in[12];
    const float* bK = (const float*)d_in[13];
    const float* WQ = (const float*)d_in[14];
    const float* bQ = (const float*)d_in[15];
    const float* WV = (const float*)d_in[16];
    const float* bV = (const float*)d_in[17];

    float* out = (float*)d_out;

    // ---- workspace layout (bytes, 256-aligned chunks) ----
    char* p = (char*)d_ws;
    auto alloc = [&](size_t bytes) {
        char* r = p;
        p += (bytes + 255) & ~(size_t)255;
        return r;
    };
    float* subj = (float*)alloc(B_ * D_ * 4);
    float* qv   = (float*)alloc(B_ * D_ * 4);
    float* tv   = (float*)alloc(B_ * D_ * 4);
    float* cb   = (float*)alloc(B_ * D_ * 4);
    float* mb   = (float*)alloc(B_ * D_ * 4);
    float* u    = (float*)alloc(D_ * 4);
    float* w    = (float*)alloc(D_ * 4);
    float* alph = (float*)alloc(256);
    float* Gu   = (float*)alloc(B_ * T_ * 4);
    float* Gw   = (float*)alloc(B_ * T_ * 4);
    float* lg   = (float*)alloc(B_ * T_ * 4);
    float* part = (float*)alloc((size_t)B_ * NCH * D_ * 4);
    float* Pt   = (float*)alloc((size_t)D_ * D_ * 4);
    short* WKb  = (short*)alloc((size_t)D_ * D_ * 2);
    short* WQb  = (short*)alloc((size_t)D_ * D_ * 2);
    short* Ptb  = (short*)alloc((size_t)D_ * D_ * 2);
    short* WVt  = (short*)alloc((size_t)D_ * D_ * 2);

    size_t fixedBytes = (size_t)(p - (char*)d_ws);
    // per-chunk bytes (nc batches): Gs + Ys + Gt + S + probs + Zs
    const size_t perBatch = (size_t)T_ * D_ * 2   // Gs
                          + (size_t)T_ * D_ * 2   // Ys
                          + (size_t)D_ * T_ * 2   // Gt
                          + (size_t)T_ * T_ * 4   // S
                          + (size_t)T_ * T_ * 2   // probs
                          + (size_t)T_ * D_ * 2;  // Zs
    int nc = 64;
    while (nc > 1 && fixedBytes + (size_t)nc * perBatch + 4096 > ws_size) nc >>= 1;

    short* Gs_c    = (short*)alloc((size_t)nc * T_ * D_ * 2);
    short* Ys_c    = (short*)alloc((size_t)nc * T_ * D_ * 2);
    short* Gt_c    = (short*)alloc((size_t)nc * D_ * T_ * 2);
    float* S_c     = (float*)alloc((size_t)nc * T_ * T_ * 4);
    short* probs_c = (short*)alloc((size_t)nc * T_ * T_ * 2);
    short* Zs_c    = (short*)alloc((size_t)nc * T_ * D_ * 2);

    // ---- small path: gate m and pooled vectors (parallel c-attention) ----
    pool_kernel<<<dim3(D_ / 256, B_), 256, 0, stream>>>(gcn, subj_pos, subj);
    mv_q<<<dim3(D_ / 256, B_), 256, 0, stream>>>(subj, Wq, bq, qv);
    mv_t<<<dim3(D_ / 256, B_), 256, 0, stream>>>(qv, Wc, bc, tv);
    vecs_kernel<<<D_ / 4, 256, 0, stream>>>(WK, WQ, bK, bQ, u, w, alph);
    att_dots<<<B_ * T_ / 4, 256, 0, stream>>>(gcn, u, w, tv, Wk, alph, bk, Gu, Gw, lg);
    ksoftmax_kernel<<<B_, 256, 0, stream>>>(lg);
    csum_part<<<dim3(D_ / 256, NCH, B_), 256, 0, stream>>>(gcn, lg, part);
    csum_reduce<<<dim3(D_ / 256, B_), 256, 0, stream>>>(part, cb);
    mv_m<<<dim3(D_ / 256, B_), 256, 0, stream>>>(cb, subj, Wm, bm, mb);

    // ---- factorization precompute (plain bf16) ----
    cast_kernel<<<512, 256, 0, stream>>>(WK, WKb, (size_t)D_ * D_ / 8);
    cast_kernel<<<512, 256, 0, stream>>>(WQ, WQb, (size_t)D_ * D_ / 8);
    // Pt[j,i] = sum_a WQ[j,a]*WK[i,a]   (used as Bt in Y-gemm: Y=G@M, M=WK@WQ^T)
    gemm_nt<0><<<dim3(8, 8, 1), 256, 0, stream>>>(WQb, 0, WKb, 0, D_, D_,
                                                  Pt, nullptr, 0, nullptr, nullptr);
    cast_kernel<<<512, 256, 0, stream>>>(Pt, Ptb, (size_t)D_ * D_ / 8);
    // WVt[d,k] = WV[k,d]
    transpose_kernel<<<dim3(32, 32, 1), 256, 0, stream>>>(WV, 0, WVt, 0, D_, D_);

    // ---- chunked attention ----
    for (int b0 = 0; b0 < B_; b0 += nc) {
        const float* Gc = gcn + (size_t)b0 * T_ * D_;
        // fused prep: Gs=bf16(G), Gt=bf16(G^T), out2 passthrough
        prep_kernel<<<dim3(D_ / 32, T_ / 32, nc), 256, 0, stream>>>(
            Gc, Gs_c, Gt_c, out + OUT2_OFF + (size_t)b0 * T_ * D_);
        // Y = G@M : A=Gs [nc*T, D], Bt=Ptb [D, D], K=D -> bf16
        gemm_nt<2><<<dim3(nc * T_ / 128, D_ / 128, 1), 256, 0, stream>>>(
            Gs_c, 0, Ptb, 0, D_, D_, nullptr, Ys_c, 0, nullptr, nullptr);
        // S = Y@G^T + Gu + Gw : A=Ys(z), Bt=Gs(z), K=D
        gemm_nt<1><<<dim3(T_ / 128, T_ / 128, nc), 256, 0, stream>>>(
            Ys_c, (size_t)T_ * D_, Gs_c, (size_t)T_ * D_, D_, T_,
            S_c, nullptr, (size_t)T_ * T_, Gu + (size_t)b0 * T_, Gw + (size_t)b0 * T_);
        // softmax: att (f32) + probs (bf16)
        softmax_att<<<dim3(T_, nc), 64, 0, stream>>>(S_c, probs_c, out + OUT3_OFF + (size_t)b0 * T_);
        // Z = probs@G : A=probs(z) [T,T], Bt=Gt(z) [D,T], K=T -> bf16
        gemm_nt<2><<<dim3(T_ / 128, D_ / 128, nc), 256, 0, stream>>>(
            probs_c, (size_t)T_ * T_, Gt_c, (size_t)D_ * T_, T_, D_,
            nullptr, Zs_c, (size_t)T_ * D_, nullptr, nullptr);
        // out0 = (Z@WV + bV) * m : A=Zs(z) [T,D], Bt=WVt [D,D], K=D
        gemm_nt<3><<<dim3(T_ / 128, D_ / 128, nc), 256, 0, stream>>>(
            Zs_c, (size_t)T_ * D_, WVt, 0, D_, D_,
            out + OUT0_OFF + (size_t)b0 * T_ * D_, nullptr, (size_t)T_ * D_,
            bV, mb + (size_t)b0 * D_);
    }

    // ---- masks passthrough ----
    masks_kernel<<<(B_ * T_ + 255) / 256, 256, 0, stream>>>(masks, out + OUT1_OFF);
}

// Round 8
// 656.017 us; speedup vs baseline: 1.6639x; 1.3783x over previous
//
#include <hip/hip_runtime.h>
#include <hip/hip_bf16.h>

#define B_ 64
#define T_ 512
#define D_ 1024
#define NCH 8   // t-chunks for c-reduction
#define TCH 64  // T_/NCH
#define PSTRIDE 12  // max partial chunks (mv_m: 3072/256)

// d_out element offsets (FLOAT32 elements)
#define OUT0_OFF 0u         // output [B,T,D]
#define OUT1_OFF 33554432u  // masks  [B,T,1]
#define OUT2_OFF 33587200u  // gcn    [B,T,D]
#define OUT3_OFF 67141632u  // att    [B,T]

typedef __attribute__((ext_vector_type(8))) short short8;
typedef __attribute__((ext_vector_type(4))) float f32x4;

__device__ __forceinline__ short bf16_of(float x) {
    __hip_bfloat16 h = __float2bfloat16(x);
    return *reinterpret_cast<short*>(&h);
}

// async global->LDS, 16B per lane; LDS dest is wave-uniform base + lane*16 (HW)
__device__ __forceinline__ void gload16(const void* g, void* l) {
    __builtin_amdgcn_global_load_lds(
        (__attribute__((address_space(1))) void*)(g),
        (__attribute__((address_space(3))) void*)(l), 16, 0, 0);
}

// ---- pool partial: partmax over 64-row t-chunk of masked gcn ----
__global__ __launch_bounds__(256) void pool_part(const float* __restrict__ gcn,
                                                 const int* __restrict__ subj_pos,
                                                 float* __restrict__ part) {
    __shared__ int keep[TCH];
    int d = blockIdx.x * 256 + threadIdx.x;
    int ch = blockIdx.y, b = blockIdx.z;
    if (threadIdx.x < TCH) keep[threadIdx.x] = (subj_pos[b * T_ + ch * TCH + threadIdx.x] == 0);
    __syncthreads();
    const float* gb = gcn + ((size_t)b * T_ + ch * TCH) * D_ + d;
    float mx = -1e12f;
    #pragma unroll 4
    for (int i = 0; i < TCH; i++) {
        float v = gb[(size_t)i * D_];
        if (keep[i]) mx = fmaxf(mx, v);
    }
    part[((size_t)b * PSTRIDE + ch) * D_ + d] = mx;
}

__global__ __launch_bounds__(256) void pool_red(const float* __restrict__ part,
                                                float* __restrict__ subj) {
    int d = blockIdx.x * 256 + threadIdx.x;
    int b = blockIdx.y;
    float mx = -1e12f;
    #pragma unroll
    for (int ch = 0; ch < NCH; ch++) mx = fmaxf(mx, part[((size_t)b * PSTRIDE + ch) * D_ + d]);
    subj[(size_t)b * D_ + d] = mx;
}

// ---- split-K matvec partial: x = [x0 (D rows) | x1 periodic]; chunk = 256 K-rows ----
__global__ __launch_bounds__(256) void mv_part(const float* __restrict__ x0,
                                               const float* __restrict__ x1,
                                               const float* __restrict__ W,
                                               float* __restrict__ part) {
    __shared__ float xs[256];
    int j = blockIdx.x * 256 + threadIdx.x;
    int ch = blockIdx.y, b = blockIdx.z;
    int gi = ch * 256 + threadIdx.x;
    xs[threadIdx.x] = (gi < D_) ? x0[(size_t)b * D_ + gi]
                                : x1[(size_t)b * D_ + ((gi - D_) & (D_ - 1))];
    __syncthreads();
    const float* Wp = W + (size_t)ch * 256 * D_ + j;
    float a0 = 0.f, a1 = 0.f, a2 = 0.f, a3 = 0.f;
    #pragma unroll 4
    for (int i = 0; i < 256; i += 4) {
        a0 += xs[i] * Wp[(size_t)i * D_];
        a1 += xs[i + 1] * Wp[(size_t)(i + 1) * D_];
        a2 += xs[i + 2] * Wp[(size_t)(i + 2) * D_];
        a3 += xs[i + 3] * Wp[(size_t)(i + 3) * D_];
    }
    part[((size_t)b * PSTRIDE + ch) * D_ + j] = (a0 + a1) + (a2 + a3);
}

// ---- reduce partials: y = relu(bias + sum_ch part) ----
__global__ __launch_bounds__(256) void mv_red(const float* __restrict__ part,
                                              const float* __restrict__ bias,
                                              float* __restrict__ y, int nch) {
    int j = blockIdx.x * 256 + threadIdx.x;
    int b = blockIdx.y;
    float acc = bias[j];
    for (int ch = 0; ch < nch; ch++) acc += part[((size_t)b * PSTRIDE + ch) * D_ + j];
    y[(size_t)b * D_ + j] = fmaxf(acc, 0.f);
}

// ---------------- u = WK@bQ, w = WQ@bK, alpha = bK.bQ ----------------
__global__ __launch_bounds__(256) void vecs_kernel(const float* __restrict__ WKm,
                                                   const float* __restrict__ WQm,
                                                   const float* __restrict__ bKv,
                                                   const float* __restrict__ bQv,
                                                   float* __restrict__ u,
                                                   float* __restrict__ w,
                                                   float* __restrict__ alpha) {
    int tid = threadIdx.x, wave = tid >> 6, lane = tid & 63;
    int row = blockIdx.x * 4 + wave;
    float s1 = 0.f, s2 = 0.f;
    for (int c = lane; c < D_; c += 64) {
        s1 += WKm[(size_t)row * D_ + c] * bQv[c];
        s2 += WQm[(size_t)row * D_ + c] * bKv[c];
    }
    #pragma unroll
    for (int off = 32; off; off >>= 1) {
        s1 += __shfl_xor(s1, off);
        s2 += __shfl_xor(s2, off);
    }
    if (lane == 0) { u[row] = s1; w[row] = s2; }
    if (blockIdx.x == 0 && wave == 0) {
        float a = 0.f;
        for (int c = lane; c < D_; c += 64) a += bKv[c] * bQv[c];
        #pragma unroll
        for (int off = 32; off; off >>= 1) a += __shfl_xor(a, off);
        if (lane == 0) alpha[0] = a;
    }
}

// ---- fused row dots: Gu[r]=g.u+alpha, Gw[r]=g.w, lg[r]=g.(tv[b]*Wk)+bk  (1 wave/row) ----
__global__ __launch_bounds__(256) void att_dots(const float* __restrict__ gcn,
                                                const float* __restrict__ u,
                                                const float* __restrict__ w,
                                                const float* __restrict__ tv,
                                                const float* __restrict__ Wk,
                                                const float* __restrict__ alpha,
                                                const float* __restrict__ bk,
                                                float* __restrict__ Gu,
                                                float* __restrict__ Gw,
                                                float* __restrict__ lg) {
    __shared__ float su[D_], sw[D_], s2[D_];
    int tid = threadIdx.x, wave = tid >> 6, lane = tid & 63;
    size_t row0 = (size_t)blockIdx.x * 4;
    int b = (int)(row0 >> 9);  // 4 rows per block share b (512 rows per b)
    for (int c = tid; c < D_; c += 256) {
        su[c] = u[c];
        sw[c] = w[c];
        s2[c] = tv[(size_t)b * D_ + c] * Wk[c];
    }
    __syncthreads();
    size_t row = row0 + wave;
    const float* g = gcn + row * D_;
    float d1 = 0.f, d2 = 0.f, d3 = 0.f;
    for (int c = lane; c < D_; c += 64) {
        float gv = g[c];
        d1 += gv * su[c];
        d2 += gv * sw[c];
        d3 += gv * s2[c];
    }
    #pragma unroll
    for (int off = 32; off; off >>= 1) {
        d1 += __shfl_xor(d1, off);
        d2 += __shfl_xor(d2, off);
        d3 += __shfl_xor(d3, off);
    }
    if (lane == 0) {
        Gu[row] = d1 + alpha[0];
        Gw[row] = d2;
        lg[row] = d3 + bk[0];
    }
}

// ---- k-softmax over T per batch, in place (lg -> normalized k) ----
__global__ __launch_bounds__(256) void ksoftmax_kernel(float* __restrict__ lg) {
    __shared__ float red[4];
    int b = blockIdx.x, tid = threadIdx.x;
    int wave = tid >> 6, lane = tid & 63;
    float* L = lg + (size_t)b * T_;
    float v0 = L[tid], v1 = L[tid + 256];
    float mx = fmaxf(v0, v1);
    #pragma unroll
    for (int off = 32; off; off >>= 1) mx = fmaxf(mx, __shfl_xor(mx, off));
    if (lane == 0) red[wave] = mx;
    __syncthreads();
    mx = fmaxf(fmaxf(red[0], red[1]), fmaxf(red[2], red[3]));
    __syncthreads();
    float e0 = expf(v0 - mx), e1 = expf(v1 - mx);
    float zs = e0 + e1;
    #pragma unroll
    for (int off = 32; off; off >>= 1) zs += __shfl_xor(zs, off);
    if (lane == 0) red[wave] = zs;
    __syncthreads();
    float invZ = 1.f / (red[0] + red[1] + red[2] + red[3]);
    L[tid] = e0 * invZ;
    L[tid + 256] = e1 * invZ;
}

// ---- partial c: part[(b*PSTRIDE+ch)*D+d] = sum_{t in chunk} k[b,t]*g[b,t,d] ----
__global__ __launch_bounds__(256) void csum_part(const float* __restrict__ gcn,
                                                 const float* __restrict__ k,
                                                 float* __restrict__ part) {
    __shared__ float kv[TCH];
    int d = blockIdx.x * 256 + threadIdx.x;
    int ch = blockIdx.y, b = blockIdx.z;
    if (threadIdx.x < TCH) kv[threadIdx.x] = k[(size_t)b * T_ + ch * TCH + threadIdx.x];
    __syncthreads();
    const float* gb = gcn + ((size_t)b * T_ + ch * TCH) * D_ + d;
    float acc = 0.f;
    #pragma unroll 4
    for (int i = 0; i < TCH; i++) acc += kv[i] * gb[(size_t)i * D_];
    part[((size_t)b * PSTRIDE + ch) * D_ + d] = acc;
}

// ---- reduce partials: c[b,d] = sum_ch part ----
__global__ __launch_bounds__(256) void csum_reduce(const float* __restrict__ part,
                                                   float* __restrict__ cbuf) {
    int d = blockIdx.x * 256 + threadIdx.x;
    int b = blockIdx.y;
    float acc = 0.f;
    #pragma unroll
    for (int ch = 0; ch < NCH; ch++) acc += part[((size_t)b * PSTRIDE + ch) * D_ + d];
    cbuf[(size_t)b * D_ + d] = acc;
}

// ---------------- plain cast f32 -> bf16, vectorized ----------------
__global__ __launch_bounds__(256) void cast_kernel(const float* __restrict__ in,
                                                   short* __restrict__ out, size_t n8) {
    size_t i = (size_t)blockIdx.x * 256 + threadIdx.x;
    size_t stride = (size_t)gridDim.x * 256;
    for (; i < n8; i += stride) {
        f32x4 v0 = ((const f32x4*)in)[2 * i];
        f32x4 v1 = ((const f32x4*)in)[2 * i + 1];
        short8 o;
        #pragma unroll
        for (int j = 0; j < 4; j++) {
            o[j] = bf16_of(v0[j]);
            o[4 + j] = bf16_of(v1[j]);
        }
        ((short8*)out)[i] = o;
    }
}

// ---- fused G-prep per chunk: Gs=bf16(G), Gt=bf16(G^T), o2=G (f32 passthrough) ----
__global__ __launch_bounds__(256) void prep_kernel(const float* __restrict__ in,
                                                   short* __restrict__ gs,
                                                   short* __restrict__ gt,
                                                   float* __restrict__ o2) {
    __shared__ float tile[32][33];
    int z = blockIdx.z;
    in += (size_t)z * T_ * D_;
    gs += (size_t)z * T_ * D_;
    gt += (size_t)z * D_ * T_;
    o2 += (size_t)z * T_ * D_;
    int c0 = blockIdx.x * 32, r0 = blockIdx.y * 32;
    int tx = threadIdx.x & 31, ty = threadIdx.x >> 5;
    #pragma unroll
    for (int i = 0; i < 4; i++) {
        int r = ty + i * 8;
        size_t idx = (size_t)(r0 + r) * D_ + c0 + tx;
        float v = in[idx];
        tile[r][tx] = v;
        o2[idx] = v;
        gs[idx] = bf16_of(v);
    }
    __syncthreads();
    #pragma unroll
    for (int i = 0; i < 4; i++) {
        int c = ty + i * 8;
        gt[(size_t)(c0 + c) * T_ + r0 + tx] = bf16_of(tile[tx][c]);
    }
}

// ---------------- out[z][c][r] = bf16(in[z][r][c]) ; R,C multiples of 32 ----------------
__global__ __launch_bounds__(256) void transpose_kernel(const float* __restrict__ in, size_t sIn,
                                                        short* __restrict__ out, size_t sOut,
                                                        int R, int C) {
    __shared__ float tile[32][33];
    int z = blockIdx.z;
    in += (size_t)z * sIn;
    out += (size_t)z * sOut;
    int c0 = blockIdx.x * 32, r0 = blockIdx.y * 32;
    int tx = threadIdx.x & 31, ty = threadIdx.x >> 5;
    #pragma unroll
    for (int i = 0; i < 4; i++) {
        int r = ty + i * 8;
        tile[r][tx] = in[(size_t)(r0 + r) * C + c0 + tx];
    }
    __syncthreads();
    #pragma unroll
    for (int i = 0; i < 4; i++) {
        int c = ty + i * 8;
        out[(size_t)(c0 + c) * R + r0 + tx] = bf16_of(tile[tx][c]);
    }
}

// ================= MFMA NT bf16 GEMM: C[m,n] = sum_k A[m,k]*Bt[n,k] =================
// 128x128 tile, BK=64, 4 waves (2x2 of 64x64), 16x16x32 bf16 MFMA, f32 accum.
// Staging: global_load_lds w16, LINEAR LDS [128][64] shorts; XOR swizzle (slot16^row&7)
// applied to the GLOBAL source on stage and to the ds_read address (both sides).
// MODE 0: f32 store | 1: f32 + Gu[row]+Gw[col] | 2: bf16 store
// MODE 3: f32 (acc+bV[col])*gate[z*D+col]
template <int MODE>
__global__ __launch_bounds__(256) void gemm_nt(
        const short* __restrict__ A, size_t sAz,
        const short* __restrict__ Bt, size_t sBz,
        int K, int ldout,
        float* __restrict__ Cf, short* __restrict__ Cb, size_t sCz,
        const float* __restrict__ e1, const float* __restrict__ e2) {
    __shared__ __align__(16) short As[128 * 64];
    __shared__ __align__(16) short Bs[128 * 64];
    int z = blockIdx.z;
    A += (size_t)z * sAz;
    Bt += (size_t)z * sBz;
    int t = threadIdx.x;
    int lane = t & 63, wave = t >> 6;
    int wr = wave >> 1, wc = wave & 1;
    size_t rowBase = (size_t)blockIdx.x * 128;
    size_t colBase = (size_t)blockIdx.y * 128;

    // ---- staging addresses: wave handles chunks wave*4+i (i=0..3); chunk = 8 rows x 128B
    int rlo = lane >> 3;                 // row within chunk 0..7
    int src16 = (lane & 7) ^ rlo;        // inverse-swizzled 16B slot in global row
    const short* gA[4];
    const short* gB[4];
    short* lA[4];
    short* lB[4];
    #pragma unroll
    for (int i = 0; i < 4; i++) {
        int ch = wave * 4 + i;
        int row = ch * 8 + rlo;
        gA[i] = A + (rowBase + row) * (size_t)K + src16 * 8;
        gB[i] = Bt + (colBase + row) * (size_t)K + src16 * 8;
        lA[i] = As + ch * 512;  // 1024B chunk; HW adds lane*16
        lB[i] = Bs + ch * 512;
    }

    f32x4 acc[4][4] = {};
    for (int kb = 0; kb < K; kb += 64) {
        __syncthreads();  // previous compute done reading LDS
        #pragma unroll
        for (int i = 0; i < 4; i++) {
            gload16(gA[i] + kb, lA[i]);
            gload16(gB[i] + kb, lB[i]);
        }
        __syncthreads();  // compiler drains vmcnt(0) before barrier
        #pragma unroll
        for (int kk = 0; kk < 2; kk++) {
            int ko16 = kk * 4 + (lane >> 4);
            int sw = ko16 ^ (lane & 7);  // row&7 == lane&7 for our row pattern
            short8 af[4], bfr[4];
            #pragma unroll
            for (int i = 0; i < 4; i++) {
                int row = wr * 64 + i * 16 + (lane & 15);
                af[i] = *(const short8*)(As + row * 64 + (sw << 3));
            }
            #pragma unroll
            for (int j = 0; j < 4; j++) {
                int row = wc * 64 + j * 16 + (lane & 15);
                bfr[j] = *(const short8*)(Bs + row * 64 + (sw << 3));
            }
            #pragma unroll
            for (int i = 0; i < 4; i++)
                #pragma unroll
                for (int j = 0; j < 4; j++)
                    acc[i][j] = __builtin_amdgcn_mfma_f32_16x16x32_bf16(af[i], bfr[j], acc[i][j], 0, 0, 0);
        }
    }
    #pragma unroll
    for (int i = 0; i < 4; i++) {
        #pragma unroll
        for (int j = 0; j < 4; j++) {
            #pragma unroll
            for (int r = 0; r < 4; r++) {
                size_t row = rowBase + wr * 64 + i * 16 + (lane >> 4) * 4 + r;
                size_t col = colBase + wc * 64 + j * 16 + (lane & 15);
                float v = acc[i][j][r];
                if (MODE == 0) {
                    Cf[z * sCz + row * ldout + col] = v;
                } else if (MODE == 1) {
                    Cf[z * sCz + row * ldout + col] = v + e1[z * T_ + row] + e2[z * T_ + col];
                } else if (MODE == 2) {
                    Cb[z * sCz + row * ldout + col] = bf16_of(v);
                } else {
                    Cf[z * sCz + row * ldout + col] = (v + e1[col]) * e2[(size_t)z * D_ + col];
                }
            }
        }
    }
}

// ---------------- per-row: att out (f32) + probs out (bf16) ----------------
__global__ __launch_bounds__(64) void softmax_att(const float* __restrict__ S,
                                                  short* __restrict__ probs,
                                                  float* __restrict__ att) {
    const float SCALE = 0.03125f;  // 1/sqrt(1024)
    int t = blockIdx.x, z = blockIdx.y, lane = threadIdx.x;
    const float* row = S + ((size_t)z * T_ + t) * T_;
    short* prow = probs + ((size_t)z * T_ + t) * T_;
    float v[8];
    float mx = -1e30f;
    #pragma unroll
    for (int k = 0; k < 8; k++) {
        v[k] = row[lane + k * 64];
        mx = fmaxf(mx, v[k]);
    }
    #pragma unroll
    for (int off = 32; off; off >>= 1) mx = fmaxf(mx, __shfl_xor(mx, off));
    float z1 = 0.f, z2 = 0.f, dg = 0.f;
    #pragma unroll
    for (int k = 0; k < 8; k++) {
        float x = v[k] - mx;
        float e1 = expf(x);
        float e2 = expf(x * SCALE);
        z1 += e1;
        z2 += e2;
        if (lane + k * 64 == t) dg = e1;
        v[k] = e2;
    }
    #pragma unroll
    for (int off = 32; off; off >>= 1) {
        z1 += __shfl_xor(z1, off);
        z2 += __shfl_xor(z2, off);
        dg += __shfl_xor(dg, off);
    }
    float inv2 = 1.f / z2;
    #pragma unroll
    for (int k = 0; k < 8; k++) prow[lane + k * 64] = bf16_of(v[k] * inv2);
    if (lane == 0) att[z * T_ + t] = SCALE * (1.f - dg / z1);
}

// ---------------- masks passthrough (f32) ----------------
__global__ __launch_bounds__(256) void masks_kernel(const int* __restrict__ masks,
                                                    float* __restrict__ out_masks) {
    int i = blockIdx.x * 256 + threadIdx.x;
    if (i < B_ * T_) out_masks[i] = (float)masks[i];
}

extern "C" void kernel_launch(void* const* d_in, const int* in_sizes, int n_in,
                              void* d_out, int out_size, void* d_ws, size_t ws_size,
                              hipStream_t stream) {
    const float* gcn = (const float*)d_in[0];
    const int* subj_pos = (const int*)d_in[1];
    const int* masks = (const int*)d_in[3];
    const float* Wq = (const float*)d_in[4];
    const float* bq = (const float*)d_in[5];
    const float* Wc = (const float*)d_in[6];
    const float* bc = (const float*)d_in[7];
    const float* Wk = (const float*)d_in[8];
    const float* bk = (const float*)d_in[9];
    const float* Wm = (const float*)d_in[10];
    const float* bm = (const float*)d_in[11];
    const float* WK = (const float*)d_in[12];
    const float* bK = (const float*)d_in[13];
    const float* WQ = (const float*)d_in[14];
    const float* bQ = (const float*)d_in[15];
    const float* WV = (const float*)d_in[16];
    const float* bV = (const float*)d_in[17];

    float* out = (float*)d_out;

    // ---- workspace layout (bytes, 256-aligned chunks) ----
    char* p = (char*)d_ws;
    auto alloc = [&](size_t bytes) {
        char* r = p;
        p += (bytes + 255) & ~(size_t)255;
        return r;
    };
    float* subj = (float*)alloc(B_ * D_ * 4);
    float* qv   = (float*)alloc(B_ * D_ * 4);
    float* tv   = (float*)alloc(B_ * D_ * 4);
    float* cb   = (float*)alloc(B_ * D_ * 4);
    float* mb   = (float*)alloc(B_ * D_ * 4);
    float* u    = (float*)alloc(D_ * 4);
    float* w    = (float*)alloc(D_ * 4);
    float* alph = (float*)alloc(256);
    float* Gu   = (float*)alloc(B_ * T_ * 4);
    float* Gw   = (float*)alloc(B_ * T_ * 4);
    float* lg   = (float*)alloc(B_ * T_ * 4);
    float* part = (float*)alloc((size_t)B_ * PSTRIDE * D_ * 4);
    float* Pt   = (float*)alloc((size_t)D_ * D_ * 4);
    short* WKb  = (short*)alloc((size_t)D_ * D_ * 2);
    short* WQb  = (short*)alloc((size_t)D_ * D_ * 2);
    short* Ptb  = (short*)alloc((size_t)D_ * D_ * 2);
    short* WVt  = (short*)alloc((size_t)D_ * D_ * 2);

    size_t fixedBytes = (size_t)(p - (char*)d_ws);
    // per-chunk bytes (nc batches): Gs + Ys + Gt + S + probs + Zs
    const size_t perBatch = (size_t)T_ * D_ * 2   // Gs
                          + (size_t)T_ * D_ * 2   // Ys
                          + (size_t)D_ * T_ * 2   // Gt
                          + (size_t)T_ * T_ * 4   // S
                          + (size_t)T_ * T_ * 2   // probs
                          + (size_t)T_ * D_ * 2;  // Zs
    int nc = 64;
    while (nc > 1 && fixedBytes + (size_t)nc * perBatch + 4096 > ws_size) nc >>= 1;

    short* Gs_c    = (short*)alloc((size_t)nc * T_ * D_ * 2);
    short* Ys_c    = (short*)alloc((size_t)nc * T_ * D_ * 2);
    short* Gt_c    = (short*)alloc((size_t)nc * D_ * T_ * 2);
    float* S_c     = (float*)alloc((size_t)nc * T_ * T_ * 4);
    short* probs_c = (short*)alloc((size_t)nc * T_ * T_ * 2);
    short* Zs_c    = (short*)alloc((size_t)nc * T_ * D_ * 2);

    // ---- small path: gate m and pooled vectors (split-K parallel matvecs) ----
    pool_part<<<dim3(D_ / 256, NCH, B_), 256, 0, stream>>>(gcn, subj_pos, part);
    pool_red<<<dim3(D_ / 256, B_), 256, 0, stream>>>(part, subj);
    mv_part<<<dim3(D_ / 256, 8, B_), 256, 0, stream>>>(subj, subj, Wq, part);
    mv_red<<<dim3(D_ / 256, B_), 256, 0, stream>>>(part, bq, qv, 8);
    mv_part<<<dim3(D_ / 256, 4, B_), 256, 0, stream>>>(qv, qv, Wc, part);
    mv_red<<<dim3(D_ / 256, B_), 256, 0, stream>>>(part, bc, tv, 4);
    vecs_kernel<<<D_ / 4, 256, 0, stream>>>(WK, WQ, bK, bQ, u, w, alph);
    att_dots<<<B_ * T_ / 4, 256, 0, stream>>>(gcn, u, w, tv, Wk, alph, bk, Gu, Gw, lg);
    ksoftmax_kernel<<<B_, 256, 0, stream>>>(lg);
    csum_part<<<dim3(D_ / 256, NCH, B_), 256, 0, stream>>>(gcn, lg, part);
    csum_reduce<<<dim3(D_ / 256, B_), 256, 0, stream>>>(part, cb);
    mv_part<<<dim3(D_ / 256, 12, B_), 256, 0, stream>>>(cb, subj, Wm, part);
    mv_red<<<dim3(D_ / 256, B_), 256, 0, stream>>>(part, bm, mb, 12);

    // ---- factorization precompute (plain bf16) ----
    cast_kernel<<<512, 256, 0, stream>>>(WK, WKb, (size_t)D_ * D_ / 8);
    cast_kernel<<<512, 256, 0, stream>>>(WQ, WQb, (size_t)D_ * D_ / 8);
    // Pt[j,i] = sum_a WQ[j,a]*WK[i,a]   (used as Bt in Y-gemm: Y=G@M, M=WK@WQ^T)
    gemm_nt<0><<<dim3(8, 8, 1), 256, 0, stream>>>(WQb, 0, WKb, 0, D_, D_,
                                                  Pt, nullptr, 0, nullptr, nullptr);
    cast_kernel<<<512, 256, 0, stream>>>(Pt, Ptb, (size_t)D_ * D_ / 8);
    // WVt[d,k] = WV[k,d]
    transpose_kernel<<<dim3(32, 32, 1), 256, 0, stream>>>(WV, 0, WVt, 0, D_, D_);

    // ---- chunked attention ----
    for (int b0 = 0; b0 < B_; b0 += nc) {
        const float* Gc = gcn + (size_t)b0 * T_ * D_;
        // fused prep: Gs=bf16(G), Gt=bf16(G^T), out2 passthrough
        prep_kernel<<<dim3(D_ / 32, T_ / 32, nc), 256, 0, stream>>>(
            Gc, Gs_c, Gt_c, out + OUT2_OFF + (size_t)b0 * T_ * D_);
        // Y = G@M : A=Gs [nc*T, D], Bt=Ptb [D, D], K=D -> bf16
        gemm_nt<2><<<dim3(nc * T_ / 128, D_ / 128, 1), 256, 0, stream>>>(
            Gs_c, 0, Ptb, 0, D_, D_, nullptr, Ys_c, 0, nullptr, nullptr);
        // S = Y@G^T + Gu + Gw : A=Ys(z), Bt=Gs(z), K=D
        gemm_nt<1><<<dim3(T_ / 128, T_ / 128, nc), 256, 0, stream>>>(
            Ys_c, (size_t)T_ * D_, Gs_c, (size_t)T_ * D_, D_, T_,
            S_c, nullptr, (size_t)T_ * T_, Gu + (size_t)b0 * T_, Gw + (size_t)b0 * T_);
        // softmax: att (f32) + probs (bf16)
        softmax_att<<<dim3(T_, nc), 64, 0, stream>>>(S_c, probs_c, out + OUT3_OFF + (size_t)b0 * T_);
        // Z = probs@G : A=probs(z) [T,T], Bt=Gt(z) [D,T], K=T -> bf16
        gemm_nt<2><<<dim3(T_ / 128, D_ / 128, nc), 256, 0, stream>>>(
            probs_c, (size_t)T_ * T_, Gt_c, (size_t)D_ * T_, T_, D_,
            nullptr, Zs_c, (size_t)T_ * D_, nullptr, nullptr);
        // out0 = (Z@WV + bV) * m : A=Zs(z) [T,D], Bt=WVt [D,D], K=D
        gemm_nt<3><<<dim3(T_ / 128, D_ / 128, nc), 256, 0, stream>>>(
            Zs_c, (size_t)T_ * D_, WVt, 0, D_, D_,
            out + OUT0_OFF + (size_t)b0 * T_ * D_, nullptr, (size_t)T_ * D_,
            bV, mb + (size_t)b0 * D_);
    }

    // ---- masks passthrough ----
    masks_kernel<<<(B_ * T_ + 255) / 256, 256, 0, stream>>>(masks, out + OUT1_OFF);
}

// Round 9
// 631.272 us; speedup vs baseline: 1.7292x; 1.0392x over previous
//
#include <hip/hip_runtime.h>
#include <hip/hip_bf16.h>

#define B_ 64
#define T_ 512
#define D_ 1024
#define NCH 8   // t-chunks for c-reduction
#define TCH 64  // T_/NCH
#define PSTRIDE 12  // max partial chunks (mv_m: 3072/256)

// d_out element offsets (FLOAT32 elements)
#define OUT0_OFF 0u         // output [B,T,D]
#define OUT1_OFF 33554432u  // masks  [B,T,1]
#define OUT2_OFF 33587200u  // gcn    [B,T,D]
#define OUT3_OFF 67141632u  // att    [B,T]

typedef __attribute__((ext_vector_type(8))) short short8;
typedef __attribute__((ext_vector_type(4))) short short4v;
typedef __attribute__((ext_vector_type(4))) float f32x4;

__device__ __forceinline__ short bf16_of(float x) {
    __hip_bfloat16 h = __float2bfloat16(x);
    return *reinterpret_cast<short*>(&h);
}

// async global->LDS, 16B per lane; LDS dest is wave-uniform base + lane*16 (HW)
__device__ __forceinline__ void gload16(const void* g, void* l) {
    __builtin_amdgcn_global_load_lds(
        (__attribute__((address_space(1))) void*)(g),
        (__attribute__((address_space(3))) void*)(l), 16, 0, 0);
}

// ---- pool partial: partmax over 64-row t-chunk of masked gcn (f32x4 lanes) ----
__global__ __launch_bounds__(256) void pool_part(const float* __restrict__ gcn,
                                                 const int* __restrict__ subj_pos,
                                                 float* __restrict__ part) {
    __shared__ int keep[TCH];
    int d = threadIdx.x * 4;  // D_ = 256*4
    int ch = blockIdx.y, b = blockIdx.z;
    if (threadIdx.x < TCH) keep[threadIdx.x] = (subj_pos[b * T_ + ch * TCH + threadIdx.x] == 0);
    __syncthreads();
    const float* gb = gcn + ((size_t)b * T_ + ch * TCH) * D_ + d;
    f32x4 mx = {-1e12f, -1e12f, -1e12f, -1e12f};
    #pragma unroll 4
    for (int i = 0; i < TCH; i++) {
        f32x4 v = *(const f32x4*)(gb + (size_t)i * D_);
        if (keep[i]) {
            mx[0] = fmaxf(mx[0], v[0]);
            mx[1] = fmaxf(mx[1], v[1]);
            mx[2] = fmaxf(mx[2], v[2]);
            mx[3] = fmaxf(mx[3], v[3]);
        }
    }
    *(f32x4*)(part + ((size_t)b * PSTRIDE + ch) * D_ + d) = mx;
}

__global__ __launch_bounds__(256) void pool_red(const float* __restrict__ part,
                                                float* __restrict__ subj) {
    int d = threadIdx.x * 4;
    int b = blockIdx.y;
    f32x4 mx = {-1e12f, -1e12f, -1e12f, -1e12f};
    #pragma unroll
    for (int ch = 0; ch < NCH; ch++) {
        f32x4 v = *(const f32x4*)(part + ((size_t)b * PSTRIDE + ch) * D_ + d);
        mx[0] = fmaxf(mx[0], v[0]);
        mx[1] = fmaxf(mx[1], v[1]);
        mx[2] = fmaxf(mx[2], v[2]);
        mx[3] = fmaxf(mx[3], v[3]);
    }
    *(f32x4*)(subj + (size_t)b * D_ + d) = mx;
}

// ---- split-K matvec partial: x = [x0 (D rows) | x1 periodic]; chunk = 256 K-rows ----
__global__ __launch_bounds__(256) void mv_part(const float* __restrict__ x0,
                                               const float* __restrict__ x1,
                                               const float* __restrict__ W,
                                               float* __restrict__ part) {
    __shared__ float xs[256];
    int j = threadIdx.x * 4;  // D_ = 256*4 cols, f32x4 per thread
    int ch = blockIdx.y, b = blockIdx.z;
    int gi = ch * 256 + threadIdx.x;
    xs[threadIdx.x] = (gi < D_) ? x0[(size_t)b * D_ + gi]
                                : x1[(size_t)b * D_ + ((gi - D_) & (D_ - 1))];
    __syncthreads();
    const float* Wp = W + (size_t)ch * 256 * D_ + j;
    f32x4 a0 = {}, a1 = {};
    #pragma unroll 4
    for (int i = 0; i < 256; i += 2) {
        f32x4 w0 = *(const f32x4*)(Wp + (size_t)i * D_);
        f32x4 w1 = *(const f32x4*)(Wp + (size_t)(i + 1) * D_);
        a0 += xs[i] * w0;
        a1 += xs[i + 1] * w1;
    }
    *(f32x4*)(part + ((size_t)b * PSTRIDE + ch) * D_ + j) = a0 + a1;
}

// ---- reduce partials: y = relu(bias + sum_ch part) ----
__global__ __launch_bounds__(256) void mv_red(const float* __restrict__ part,
                                              const float* __restrict__ bias,
                                              float* __restrict__ y, int nch) {
    int j = threadIdx.x * 4;
    int b = blockIdx.y;
    f32x4 acc = *(const f32x4*)(bias + j);
    for (int ch = 0; ch < nch; ch++)
        acc += *(const f32x4*)(part + ((size_t)b * PSTRIDE + ch) * D_ + j);
    #pragma unroll
    for (int q = 0; q < 4; q++) acc[q] = fmaxf(acc[q], 0.f);
    *(f32x4*)(y + (size_t)b * D_ + j) = acc;
}

// ---------------- u = WK@bQ, w = WQ@bK, alpha = bK.bQ ----------------
__global__ __launch_bounds__(256) void vecs_kernel(const float* __restrict__ WKm,
                                                   const float* __restrict__ WQm,
                                                   const float* __restrict__ bKv,
                                                   const float* __restrict__ bQv,
                                                   float* __restrict__ u,
                                                   float* __restrict__ w,
                                                   float* __restrict__ alpha) {
    int tid = threadIdx.x, wave = tid >> 6, lane = tid & 63;
    int row = blockIdx.x * 4 + wave;
    float s1 = 0.f, s2 = 0.f;
    for (int c = lane; c < D_; c += 64) {
        s1 += WKm[(size_t)row * D_ + c] * bQv[c];
        s2 += WQm[(size_t)row * D_ + c] * bKv[c];
    }
    #pragma unroll
    for (int off = 32; off; off >>= 1) {
        s1 += __shfl_xor(s1, off);
        s2 += __shfl_xor(s2, off);
    }
    if (lane == 0) { u[row] = s1; w[row] = s2; }
    if (blockIdx.x == 0 && wave == 0) {
        float a = 0.f;
        for (int c = lane; c < D_; c += 64) a += bKv[c] * bQv[c];
        #pragma unroll
        for (int off = 32; off; off >>= 1) a += __shfl_xor(a, off);
        if (lane == 0) alpha[0] = a;
    }
}

// ---- fused row dots: Gu[r]=g.u+alpha, Gw[r]=g.w, lg[r]=g.(tv[b]*Wk)+bk  (1 wave/row, f32x4) ----
__global__ __launch_bounds__(256) void att_dots(const float* __restrict__ gcn,
                                                const float* __restrict__ u,
                                                const float* __restrict__ w,
                                                const float* __restrict__ tv,
                                                const float* __restrict__ Wk,
                                                const float* __restrict__ alpha,
                                                const float* __restrict__ bk,
                                                float* __restrict__ Gu,
                                                float* __restrict__ Gw,
                                                float* __restrict__ lg) {
    __shared__ float su[D_], sw[D_], s2[D_];
    int tid = threadIdx.x, wave = tid >> 6, lane = tid & 63;
    size_t row0 = (size_t)blockIdx.x * 4;
    int b = (int)(row0 >> 9);  // 4 rows per block share b (512 rows per b)
    for (int c = tid; c < D_; c += 256) {
        su[c] = u[c];
        sw[c] = w[c];
        s2[c] = tv[(size_t)b * D_ + c] * Wk[c];
    }
    __syncthreads();
    size_t row = row0 + wave;
    const float* g = gcn + row * D_;
    float d1 = 0.f, d2 = 0.f, d3 = 0.f;
    #pragma unroll
    for (int it = 0; it < 4; it++) {
        int c = lane * 4 + it * 256;
        f32x4 gv = *(const f32x4*)(g + c);
        f32x4 uu = *(const f32x4*)(su + c);
        f32x4 ww = *(const f32x4*)(sw + c);
        f32x4 kk = *(const f32x4*)(s2 + c);
        #pragma unroll
        for (int q = 0; q < 4; q++) {
            d1 += gv[q] * uu[q];
            d2 += gv[q] * ww[q];
            d3 += gv[q] * kk[q];
        }
    }
    #pragma unroll
    for (int off = 32; off; off >>= 1) {
        d1 += __shfl_xor(d1, off);
        d2 += __shfl_xor(d2, off);
        d3 += __shfl_xor(d3, off);
    }
    if (lane == 0) {
        Gu[row] = d1 + alpha[0];
        Gw[row] = d2;
        lg[row] = d3 + bk[0];
    }
}

// ---- k-softmax over T per batch, in place (lg -> normalized k) ----
__global__ __launch_bounds__(256) void ksoftmax_kernel(float* __restrict__ lg) {
    __shared__ float red[4];
    int b = blockIdx.x, tid = threadIdx.x;
    int wave = tid >> 6, lane = tid & 63;
    float* L = lg + (size_t)b * T_;
    float v0 = L[tid], v1 = L[tid + 256];
    float mx = fmaxf(v0, v1);
    #pragma unroll
    for (int off = 32; off; off >>= 1) mx = fmaxf(mx, __shfl_xor(mx, off));
    if (lane == 0) red[wave] = mx;
    __syncthreads();
    mx = fmaxf(fmaxf(red[0], red[1]), fmaxf(red[2], red[3]));
    __syncthreads();
    float e0 = expf(v0 - mx), e1 = expf(v1 - mx);
    float zs = e0 + e1;
    #pragma unroll
    for (int off = 32; off; off >>= 1) zs += __shfl_xor(zs, off);
    if (lane == 0) red[wave] = zs;
    __syncthreads();
    float invZ = 1.f / (red[0] + red[1] + red[2] + red[3]);
    L[tid] = e0 * invZ;
    L[tid + 256] = e1 * invZ;
}

// ---- partial c: part[(b*PSTRIDE+ch)*D+d] = sum_{t in chunk} k[b,t]*g[b,t,d] (f32x4) ----
__global__ __launch_bounds__(256) void csum_part(const float* __restrict__ gcn,
                                                 const float* __restrict__ k,
                                                 float* __restrict__ part) {
    __shared__ float kv[TCH];
    int d = threadIdx.x * 4;
    int ch = blockIdx.y, b = blockIdx.z;
    if (threadIdx.x < TCH) kv[threadIdx.x] = k[(size_t)b * T_ + ch * TCH + threadIdx.x];
    __syncthreads();
    const float* gb = gcn + ((size_t)b * T_ + ch * TCH) * D_ + d;
    f32x4 acc = {};
    #pragma unroll 4
    for (int i = 0; i < TCH; i++) acc += kv[i] * *(const f32x4*)(gb + (size_t)i * D_);
    *(f32x4*)(part + ((size_t)b * PSTRIDE + ch) * D_ + d) = acc;
}

// ---- reduce partials: c[b,d] = sum_ch part ----
__global__ __launch_bounds__(256) void csum_reduce(const float* __restrict__ part,
                                                   float* __restrict__ cbuf) {
    int d = threadIdx.x * 4;
    int b = blockIdx.y;
    f32x4 acc = {};
    #pragma unroll
    for (int ch = 0; ch < NCH; ch++)
        acc += *(const f32x4*)(part + ((size_t)b * PSTRIDE + ch) * D_ + d);
    *(f32x4*)(cbuf + (size_t)b * D_ + d) = acc;
}

// ---------------- plain cast f32 -> bf16, vectorized ----------------
__global__ __launch_bounds__(256) void cast_kernel(const float* __restrict__ in,
                                                   short* __restrict__ out, size_t n8) {
    size_t i = (size_t)blockIdx.x * 256 + threadIdx.x;
    size_t stride = (size_t)gridDim.x * 256;
    for (; i < n8; i += stride) {
        f32x4 v0 = ((const f32x4*)in)[2 * i];
        f32x4 v1 = ((const f32x4*)in)[2 * i + 1];
        short8 o;
        #pragma unroll
        for (int j = 0; j < 4; j++) {
            o[j] = bf16_of(v0[j]);
            o[4 + j] = bf16_of(v1[j]);
        }
        ((short8*)out)[i] = o;
    }
}

// ---- fused G-prep per chunk: Gs=bf16(G), Gt=bf16(G^T), o2=G (f32 passthrough); f32x4 IO ----
__global__ __launch_bounds__(256) void prep_kernel(const float* __restrict__ in,
                                                   short* __restrict__ gs,
                                                   short* __restrict__ gt,
                                                   float* __restrict__ o2) {
    __shared__ float tile[32][33];
    int z = blockIdx.z;
    in += (size_t)z * T_ * D_;
    gs += (size_t)z * T_ * D_;
    gt += (size_t)z * D_ * T_;
    o2 += (size_t)z * T_ * D_;
    int c0 = blockIdx.x * 32, r0 = blockIdx.y * 32;
    int tx = threadIdx.x & 7, ty = threadIdx.x >> 3;  // 8 f32x4-cols x 32 rows
    {
        size_t idx = (size_t)(r0 + ty) * D_ + c0 + tx * 4;
        f32x4 v = *(const f32x4*)(in + idx);
        *(f32x4*)(o2 + idx) = v;
        short4v s;
        #pragma unroll
        for (int q = 0; q < 4; q++) {
            s[q] = bf16_of(v[q]);
            tile[ty][tx * 4 + q] = v[q];
        }
        *(short4v*)(gs + idx) = s;
    }
    __syncthreads();
    int tx2 = threadIdx.x & 31, ty2 = threadIdx.x >> 5;
    #pragma unroll
    for (int i = 0; i < 4; i++) {
        int c = ty2 + i * 8;
        gt[(size_t)(c0 + c) * T_ + r0 + tx2] = bf16_of(tile[tx2][c]);
    }
}

// ---------------- out[z][c][r] = bf16(in[z][r][c]) ; R,C multiples of 32 ----------------
__global__ __launch_bounds__(256) void transpose_kernel(const float* __restrict__ in, size_t sIn,
                                                        short* __restrict__ out, size_t sOut,
                                                        int R, int C) {
    __shared__ float tile[32][33];
    int z = blockIdx.z;
    in += (size_t)z * sIn;
    out += (size_t)z * sOut;
    int c0 = blockIdx.x * 32, r0 = blockIdx.y * 32;
    int tx = threadIdx.x & 31, ty = threadIdx.x >> 5;
    #pragma unroll
    for (int i = 0; i < 4; i++) {
        int r = ty + i * 8;
        tile[r][tx] = in[(size_t)(r0 + r) * C + c0 + tx];
    }
    __syncthreads();
    #pragma unroll
    for (int i = 0; i < 4; i++) {
        int c = ty + i * 8;
        out[(size_t)(c0 + c) * R + r0 + tx] = bf16_of(tile[tx][c]);
    }
}

// ================= MFMA NT bf16 GEMM: C[m,n] = sum_k A[m,k]*Bt[n,k] =================
// 128x128 tile, BK=64, 4 waves (2x2 of 64x64), 16x16x32 bf16 MFMA, f32 accum.
// Staging: global_load_lds w16, LINEAR LDS [128][64] shorts; XOR swizzle (slot16^row&7)
// applied to the GLOBAL source on stage and to the ds_read address (both sides).
// XCD-aware bijective block swizzle: contiguous tile chunks per XCD (grid%8==0).
// MODE 0: f32 store | 1: f32 + Gu[row]+Gw[col] | 2: bf16 store
// MODE 3: f32 (acc+bV[col])*gate[z*D+col]
template <int MODE>
__global__ __launch_bounds__(256) void gemm_nt(
        const short* __restrict__ A, size_t sAz,
        const short* __restrict__ Bt, size_t sBz,
        int K, int ldout,
        float* __restrict__ Cf, short* __restrict__ Cb, size_t sCz,
        const float* __restrict__ e1, const float* __restrict__ e2) {
    __shared__ __align__(16) short As[128 * 64];
    __shared__ __align__(16) short Bs[128 * 64];
    // ---- XCD swizzle: hw block lin (on XCD lin%8) -> tile swz = (lin%8)*(tot/8)+lin/8
    unsigned gx = gridDim.x, gy = gridDim.y;
    unsigned lin = blockIdx.x + gx * (blockIdx.y + gy * blockIdx.z);
    unsigned tot = gx * gy * gridDim.z;
    unsigned swz = (lin & 7u) * (tot >> 3) + (lin >> 3);
    unsigned bx = swz % gx;
    unsigned tmp = swz / gx;
    unsigned by = tmp % gy;
    unsigned bz = tmp / gy;

    int z = bz;
    A += (size_t)z * sAz;
    Bt += (size_t)z * sBz;
    int t = threadIdx.x;
    int lane = t & 63, wave = t >> 6;
    int wr = wave >> 1, wc = wave & 1;
    size_t rowBase = (size_t)bx * 128;
    size_t colBase = (size_t)by * 128;

    // ---- staging addresses: wave handles chunks wave*4+i (i=0..3); chunk = 8 rows x 128B
    int rlo = lane >> 3;                 // row within chunk 0..7
    int src16 = (lane & 7) ^ rlo;        // inverse-swizzled 16B slot in global row
    const short* gA[4];
    const short* gB[4];
    short* lA[4];
    short* lB[4];
    #pragma unroll
    for (int i = 0; i < 4; i++) {
        int ch = wave * 4 + i;
        int row = ch * 8 + rlo;
        gA[i] = A + (rowBase + row) * (size_t)K + src16 * 8;
        gB[i] = Bt + (colBase + row) * (size_t)K + src16 * 8;
        lA[i] = As + ch * 512;  // 1024B chunk; HW adds lane*16
        lB[i] = Bs + ch * 512;
    }

    f32x4 acc[4][4] = {};
    for (int kb = 0; kb < K; kb += 64) {
        __syncthreads();  // previous compute done reading LDS
        #pragma unroll
        for (int i = 0; i < 4; i++) {
            gload16(gA[i] + kb, lA[i]);
            gload16(gB[i] + kb, lB[i]);
        }
        __syncthreads();  // compiler drains vmcnt(0) before barrier
        #pragma unroll
        for (int kk = 0; kk < 2; kk++) {
            int ko16 = kk * 4 + (lane >> 4);
            int sw = ko16 ^ (lane & 7);  // row&7 == lane&7 for our row pattern
            short8 af[4], bfr[4];
            #pragma unroll
            for (int i = 0; i < 4; i++) {
                int row = wr * 64 + i * 16 + (lane & 15);
                af[i] = *(const short8*)(As + row * 64 + (sw << 3));
            }
            #pragma unroll
            for (int j = 0; j < 4; j++) {
                int row = wc * 64 + j * 16 + (lane & 15);
                bfr[j] = *(const short8*)(Bs + row * 64 + (sw << 3));
            }
            #pragma unroll
            for (int i = 0; i < 4; i++)
                #pragma unroll
                for (int j = 0; j < 4; j++)
                    acc[i][j] = __builtin_amdgcn_mfma_f32_16x16x32_bf16(af[i], bfr[j], acc[i][j], 0, 0, 0);
        }
    }
    #pragma unroll
    for (int i = 0; i < 4; i++) {
        #pragma unroll
        for (int j = 0; j < 4; j++) {
            #pragma unroll
            for (int r = 0; r < 4; r++) {
                size_t row = rowBase + wr * 64 + i * 16 + (lane >> 4) * 4 + r;
                size_t col = colBase + wc * 64 + j * 16 + (lane & 15);
                float v = acc[i][j][r];
                if (MODE == 0) {
                    Cf[z * sCz + row * ldout + col] = v;
                } else if (MODE == 1) {
                    Cf[z * sCz + row * ldout + col] = v + e1[z * T_ + row] + e2[z * T_ + col];
                } else if (MODE == 2) {
                    Cb[z * sCz + row * ldout + col] = bf16_of(v);
                } else {
                    Cf[z * sCz + row * ldout + col] = (v + e1[col]) * e2[(size_t)z * D_ + col];
                }
            }
        }
    }
}

// ---------------- per-row: att out (f32) + probs out (bf16); 4 rows/block ----------------
__global__ __launch_bounds__(256) void softmax_att(const float* __restrict__ S,
                                                   short* __restrict__ probs,
                                                   float* __restrict__ att) {
    const float SCALE = 0.03125f;  // 1/sqrt(1024)
    int wave = threadIdx.x >> 6, lane = threadIdx.x & 63;
    int t = blockIdx.x * 4 + wave, z = blockIdx.y;
    const float* row = S + ((size_t)z * T_ + t) * T_;
    short* prow = probs + ((size_t)z * T_ + t) * T_;
    float v[8];
    float mx = -1e30f;
    #pragma unroll
    for (int k = 0; k < 8; k++) {
        v[k] = row[lane + k * 64];
        mx = fmaxf(mx, v[k]);
    }
    #pragma unroll
    for (int off = 32; off; off >>= 1) mx = fmaxf(mx, __shfl_xor(mx, off));
    float z1 = 0.f, z2 = 0.f, dg = 0.f;
    #pragma unroll
    for (int k = 0; k < 8; k++) {
        float x = v[k] - mx;
        float e1 = expf(x);
        float e2 = expf(x * SCALE);
        z1 += e1;
        z2 += e2;
        if (lane + k * 64 == t) dg = e1;
        v[k] = e2;
    }
    #pragma unroll
    for (int off = 32; off; off >>= 1) {
        z1 += __shfl_xor(z1, off);
        z2 += __shfl_xor(z2, off);
        dg += __shfl_xor(dg, off);
    }
    float inv2 = 1.f / z2;
    #pragma unroll
    for (int k = 0; k < 8; k++) prow[lane + k * 64] = bf16_of(v[k] * inv2);
    if (lane == 0) att[z * T_ + t] = SCALE * (1.f - dg / z1);
}

// ---------------- masks passthrough (f32) ----------------
__global__ __launch_bounds__(256) void masks_kernel(const int* __restrict__ masks,
                                                    float* __restrict__ out_masks) {
    int i = blockIdx.x * 256 + threadIdx.x;
    if (i < B_ * T_) out_masks[i] = (float)masks[i];
}

extern "C" void kernel_launch(void* const* d_in, const int* in_sizes, int n_in,
                              void* d_out, int out_size, void* d_ws, size_t ws_size,
                              hipStream_t stream) {
    const float* gcn = (const float*)d_in[0];
    const int* subj_pos = (const int*)d_in[1];
    const int* masks = (const int*)d_in[3];
    const float* Wq = (const float*)d_in[4];
    const float* bq = (const float*)d_in[5];
    const float* Wc = (const float*)d_in[6];
    const float* bc = (const float*)d_in[7];
    const float* Wk = (const float*)d_in[8];
    const float* bk = (const float*)d_in[9];
    const float* Wm = (const float*)d_in[10];
    const float* bm = (const float*)d_in[11];
    const float* WK = (const float*)d_in[12];
    const float* bK = (const float*)d_in[13];
    const float* WQ = (const float*)d_in[14];
    const float* bQ = (const float*)d_in[15];
    const float* WV = (const float*)d_in[16];
    const float* bV = (const float*)d_in[17];

    float* out = (float*)d_out;

    // ---- workspace layout (bytes, 256-aligned chunks) ----
    char* p = (char*)d_ws;
    auto alloc = [&](size_t bytes) {
        char* r = p;
        p += (bytes + 255) & ~(size_t)255;
        return r;
    };
    float* subj = (float*)alloc(B_ * D_ * 4);
    float* qv   = (float*)alloc(B_ * D_ * 4);
    float* tv   = (float*)alloc(B_ * D_ * 4);
    float* cb   = (float*)alloc(B_ * D_ * 4);
    float* mb   = (float*)alloc(B_ * D_ * 4);
    float* u    = (float*)alloc(D_ * 4);
    float* w    = (float*)alloc(D_ * 4);
    float* alph = (float*)alloc(256);
    float* Gu   = (float*)alloc(B_ * T_ * 4);
    float* Gw   = (float*)alloc(B_ * T_ * 4);
    float* lg   = (float*)alloc(B_ * T_ * 4);
    float* part = (float*)alloc((size_t)B_ * PSTRIDE * D_ * 4);
    float* Pt   = (float*)alloc((size_t)D_ * D_ * 4);
    short* WKb  = (short*)alloc((size_t)D_ * D_ * 2);
    short* WQb  = (short*)alloc((size_t)D_ * D_ * 2);
    short* Ptb  = (short*)alloc((size_t)D_ * D_ * 2);
    short* WVt  = (short*)alloc((size_t)D_ * D_ * 2);

    size_t fixedBytes = (size_t)(p - (char*)d_ws);
    const size_t perBatch = (size_t)T_ * D_ * 2   // Gs
                          + (size_t)T_ * D_ * 2   // Ys
                          + (size_t)D_ * T_ * 2   // Gt
                          + (size_t)T_ * T_ * 4   // S
                          + (size_t)T_ * T_ * 2   // probs
                          + (size_t)T_ * D_ * 2;  // Zs
    int nc = 64;
    while (nc > 1 && fixedBytes + (size_t)nc * perBatch + 4096 > ws_size) nc >>= 1;

    short* Gs_c    = (short*)alloc((size_t)nc * T_ * D_ * 2);
    short* Ys_c    = (short*)alloc((size_t)nc * T_ * D_ * 2);
    short* Gt_c    = (short*)alloc((size_t)nc * D_ * T_ * 2);
    float* S_c     = (float*)alloc((size_t)nc * T_ * T_ * 4);
    short* probs_c = (short*)alloc((size_t)nc * T_ * T_ * 2);
    short* Zs_c    = (short*)alloc((size_t)nc * T_ * D_ * 2);

    // ---- small path: gate m and pooled vectors (split-K parallel, vectorized) ----
    pool_part<<<dim3(1, NCH, B_), 256, 0, stream>>>(gcn, subj_pos, part);
    pool_red<<<dim3(1, B_), 256, 0, stream>>>(part, subj);
    mv_part<<<dim3(1, 8, B_), 256, 0, stream>>>(subj, subj, Wq, part);
    mv_red<<<dim3(1, B_), 256, 0, stream>>>(part, bq, qv, 8);
    mv_part<<<dim3(1, 4, B_), 256, 0, stream>>>(qv, qv, Wc, part);
    mv_red<<<dim3(1, B_), 256, 0, stream>>>(part, bc, tv, 4);
    vecs_kernel<<<D_ / 4, 256, 0, stream>>>(WK, WQ, bK, bQ, u, w, alph);
    att_dots<<<B_ * T_ / 4, 256, 0, stream>>>(gcn, u, w, tv, Wk, alph, bk, Gu, Gw, lg);
    ksoftmax_kernel<<<B_, 256, 0, stream>>>(lg);
    csum_part<<<dim3(1, NCH, B_), 256, 0, stream>>>(gcn, lg, part);
    csum_reduce<<<dim3(1, B_), 256, 0, stream>>>(part, cb);
    mv_part<<<dim3(1, 12, B_), 256, 0, stream>>>(cb, subj, Wm, part);
    mv_red<<<dim3(1, B_), 256, 0, stream>>>(part, bm, mb, 12);

    // ---- factorization precompute (plain bf16) ----
    cast_kernel<<<512, 256, 0, stream>>>(WK, WKb, (size_t)D_ * D_ / 8);
    cast_kernel<<<512, 256, 0, stream>>>(WQ, WQb, (size_t)D_ * D_ / 8);
    gemm_nt<0><<<dim3(8, 8, 1), 256, 0, stream>>>(WQb, 0, WKb, 0, D_, D_,
                                                  Pt, nullptr, 0, nullptr, nullptr);
    cast_kernel<<<512, 256, 0, stream>>>(Pt, Ptb, (size_t)D_ * D_ / 8);
    transpose_kernel<<<dim3(32, 32, 1), 256, 0, stream>>>(WV, 0, WVt, 0, D_, D_);

    // ---- chunked attention ----
    for (int b0 = 0; b0 < B_; b0 += nc) {
        const float* Gc = gcn + (size_t)b0 * T_ * D_;
        prep_kernel<<<dim3(D_ / 32, T_ / 32, nc), 256, 0, stream>>>(
            Gc, Gs_c, Gt_c, out + OUT2_OFF + (size_t)b0 * T_ * D_);
        // Y = G@M
        gemm_nt<2><<<dim3(nc * T_ / 128, D_ / 128, 1), 256, 0, stream>>>(
            Gs_c, 0, Ptb, 0, D_, D_, nullptr, Ys_c, 0, nullptr, nullptr);
        // S = Y@G^T + Gu + Gw
        gemm_nt<1><<<dim3(T_ / 128, T_ / 128, nc), 256, 0, stream>>>(
            Ys_c, (size_t)T_ * D_, Gs_c, (size_t)T_ * D_, D_, T_,
            S_c, nullptr, (size_t)T_ * T_, Gu + (size_t)b0 * T_, Gw + (size_t)b0 * T_);
        // softmax: att (f32) + probs (bf16)
        softmax_att<<<dim3(T_ / 4, nc), 256, 0, stream>>>(S_c, probs_c, out + OUT3_OFF + (size_t)b0 * T_);
        // Z = probs@G
        gemm_nt<2><<<dim3(T_ / 128, D_ / 128, nc), 256, 0, stream>>>(
            probs_c, (size_t)T_ * T_, Gt_c, (size_t)D_ * T_, T_, D_,
            nullptr, Zs_c, (size_t)T_ * D_, nullptr, nullptr);
        // out0 = (Z@WV + bV) * m
        gemm_nt<3><<<dim3(T_ / 128, D_ / 128, nc), 256, 0, stream>>>(
            Zs_c, (size_t)T_ * D_, WVt, 0, D_, D_,
            out + OUT0_OFF + (size_t)b0 * T_ * D_, nullptr, (size_t)T_ * D_,
            bV, mb + (size_t)b0 * D_);
    }

    // ---- masks passthrough ----
    masks_kernel<<<(B_ * T_ + 255) / 256, 256, 0, stream>>>(masks, out + OUT1_OFF);
}